// Round 1
// 1879.538 us; speedup vs baseline: 1.1218x; 1.1218x over previous
//
#include <hip/hip_runtime.h>
#include <cmath>

#define D_MODEL 512
#define T_TOK   4096
#define S_SEQ   1024
#define DH_FF   2048
#define N_EXP   8
#define CAP     9216    // 8192 assignments + 8*127 pad, 128-aligned
#define CHUNK   256     // MoE hidden-dim chunk
#define QKV_LD  1536

typedef __attribute__((ext_vector_type(8))) short bf16x8_t;
typedef __attribute__((ext_vector_type(4))) float f32x4_t;
typedef _Float16 f16x8 __attribute__((ext_vector_type(8)));

__device__ __forceinline__ float gelu_exact(float x) {
    return 0.5f * x * (1.0f + erff(x * 0.70710678118654752440f));
}
__device__ __forceinline__ unsigned short f2bf(float f) {
    union { float f; unsigned int u; } v; v.f = f;
    unsigned int r = v.u + 0x7fff + ((v.u >> 16) & 1);   // RNE
    return (unsigned short)(r >> 16);
}
__device__ __forceinline__ float bf2f(unsigned short u) {
    union { unsigned int i; float f; } v; v.i = ((unsigned int)u) << 16; return v.f;
}
__device__ __forceinline__ unsigned short f2h(float f) {
    _Float16 h = (_Float16)f;
    return __builtin_bit_cast(unsigned short, h);
}
// fp32 -> fp16 hi + fp16 lo (Ootomo split): v ~= hi + lo, rel err ~2^-22
__device__ __forceinline__ void split1(float v, unsigned short& h, unsigned short& l) {
    _Float16 hf = (_Float16)v;
    _Float16 lf = (_Float16)(v - (float)hf);
    h = __builtin_bit_cast(unsigned short, hf);
    l = __builtin_bit_cast(unsigned short, lf);
}

// ---------------- LayerNorm: fp32 in -> fp32 out (+ optional bf16 copy) ----------------
__global__ __launch_bounds__(256) void ln_kernel(
    const float* __restrict__ x, const float* __restrict__ w,
    const float* __restrict__ b, float* __restrict__ out,
    unsigned short* __restrict__ outb)
{
    const int t = blockIdx.x, tid = threadIdx.x;
    const float* xr = x + (size_t)t * D_MODEL;
    float v0 = xr[tid], v1 = xr[tid + 256];
    __shared__ float ss[256], sq[256];
    ss[tid] = v0 + v1;
    sq[tid] = v0 * v0 + v1 * v1;
    __syncthreads();
    for (int st = 128; st > 0; st >>= 1) {
        if (tid < st) { ss[tid] += ss[tid + st]; sq[tid] += sq[tid + st]; }
        __syncthreads();
    }
    float mu  = ss[0] * (1.0f / 512.0f);
    float var = sq[0] * (1.0f / 512.0f) - mu * mu;
    float rs  = rsqrtf(var + 1e-6f);
    float o0 = (v0 - mu) * rs * w[tid]       + b[tid];
    float o1 = (v1 - mu) * rs * w[tid + 256] + b[tid + 256];
    float* outr = out + (size_t)t * D_MODEL;
    outr[tid] = o0; outr[tid + 256] = o1;
    if (outb) {
        unsigned short* ob = outb + (size_t)t * D_MODEL;
        ob[tid] = f2bf(o0); ob[tid + 256] = f2bf(o1);
    }
}

// ------- Transpose-split: fp32 [K,N] slab -> fp16 hi[N,K] + lo[N,K] -------
__global__ __launch_bounds__(256) void tconv_split(
    const float* __restrict__ in, int inLd, size_t eStrideIn,
    unsigned short* __restrict__ outHi, unsigned short* __restrict__ outLo,
    int outLd, size_t eStrideOut)
{
    __shared__ float Ts[32][33];
    const int tid = threadIdx.x;
    const int k0 = blockIdx.y * 32, n0 = blockIdx.x * 32;
    in    += (size_t)blockIdx.z * eStrideIn;
    outHi += (size_t)blockIdx.z * eStrideOut;
    outLo += (size_t)blockIdx.z * eStrideOut;
    int r = tid >> 3, c = (tid & 7) * 4;
    float4 v = *(const float4*)&in[(size_t)(k0 + r) * inLd + n0 + c];
    Ts[r][c] = v.x; Ts[r][c + 1] = v.y; Ts[r][c + 2] = v.z; Ts[r][c + 3] = v.w;
    __syncthreads();
    int n = tid >> 3, kk = (tid & 7) * 4;
    ushort4 h4, l4;
    split1(Ts[kk][n],     h4.x, l4.x); split1(Ts[kk + 1][n], h4.y, l4.y);
    split1(Ts[kk + 2][n], h4.z, l4.z); split1(Ts[kk + 3][n], h4.w, l4.w);
    size_t o = (size_t)(n0 + n) * outLd + k0 + kk;
    *(ushort4*)&outHi[o] = h4;
    *(ushort4*)&outLo[o] = l4;
}

// ------- Transpose-convert bf16 (validated, L2 MoE) -------
__global__ __launch_bounds__(256) void tconv(
    const float* __restrict__ in, int inLd, size_t eStrideIn,
    unsigned short* __restrict__ out, int outLd, size_t eStrideOut)
{
    __shared__ float Ts[32][33];
    const int tid = threadIdx.x;
    const int k0 = blockIdx.y * 32, n0 = blockIdx.x * 32;
    in  += (size_t)blockIdx.z * eStrideIn;
    out += (size_t)blockIdx.z * eStrideOut;
    int r = tid >> 3, c = (tid & 7) * 4;
    float4 v = *(const float4*)&in[(size_t)(k0 + r) * inLd + n0 + c];
    Ts[r][c] = v.x; Ts[r][c + 1] = v.y; Ts[r][c + 2] = v.z; Ts[r][c + 3] = v.w;
    __syncthreads();
    int n = tid >> 3, kk = (tid & 7) * 4;
    ushort4 o;
    o.x = f2bf(Ts[kk][n]);     o.y = f2bf(Ts[kk + 1][n]);
    o.z = f2bf(Ts[kk + 2][n]); o.w = f2bf(Ts[kk + 3][n]);
    *(ushort4*)&out[(size_t)(n0 + n) * outLd + k0 + kk] = o;
}

// ---------------- fp16x3 MFMA GEMM (fp32-grade accuracy), 128x128 tiles ----------------
// A fp32 row-major (split on the fly); Bt pre-split fp16 hi/lo, [N][K] K-contiguous.
// MODE 0: C fp32 = acc                 (qkv proj, ldc=1536)
// MODE 1: C fp32 = acc + bias + resid  (o proj)
// MODE 2: C fp32 = gelu(acc+bias_e), A gathered via rowtok (MoE up)
// MODE 3: C fp32 (+)= acc              (MoE down, per-expert B)
template<int MODE>
__global__ __launch_bounds__(256) void gemm_f16x3(
    const float* __restrict__ A, int lda, int KLEN,
    const unsigned short* __restrict__ BtHi, const unsigned short* __restrict__ BtLo,
    int ldBk, size_t BeStride,
    float* __restrict__ C, int ldc,
    const float* __restrict__ bias, int biasStride,
    const float* __restrict__ resid,
    const int* __restrict__ offs, const int* __restrict__ rowtok, int beta)
{
    __shared__ unsigned short As_hi[128 * 32], As_lo[128 * 32];
    __shared__ unsigned short Bs_hi[128 * 32], Bs_lo[128 * 32];
    __shared__ int rt[128];
    const int tid = threadIdx.x;
    const int row0 = blockIdx.y * 128, col0 = blockIdx.x * 128;
    int e = 0;
    if (MODE >= 2) {
        #pragma unroll
        for (int i = 1; i < N_EXP; i++) if (offs[i] <= row0) e = i;
    }
    if (MODE == 2) {
        for (int i = tid; i < 128; i += 256) rt[i] = rowtok[row0 + i];
        __syncthreads();
    }
    const unsigned short* BeHi = BtHi + (size_t)e * BeStride;
    const unsigned short* BeLo = BtLo + (size_t)e * BeStride;
    const int lane = tid & 63, w = tid >> 6;
    const int wrow = (w >> 1) * 64, wcol = (w & 1) * 64;
    const int m_ = lane & 15, q_ = lane >> 4;
    f32x4_t acc[4][4];
    #pragma unroll
    for (int i = 0; i < 4; i++)
        #pragma unroll
        for (int j = 0; j < 4; j++) acc[i][j] = (f32x4_t){0.f, 0.f, 0.f, 0.f};

    const int ar = tid >> 1, ac0 = (tid & 1) * 16;
    for (int k0 = 0; k0 < KLEN; k0 += 32) {
        {
            const float* Arow;
            bool zero = false;
            if (MODE == 2) {
                int t = rt[ar];
                zero = (t < 0);
                Arow = A + (size_t)(zero ? 0 : t) * lda;
            } else {
                Arow = A + (size_t)(row0 + ar) * lda;
            }
            #pragma unroll
            for (int q = 0; q < 4; q++) {
                float4 f = zero ? make_float4(0.f, 0.f, 0.f, 0.f)
                                : *(const float4*)&Arow[k0 + ac0 + 4 * q];
                ushort4 h4, l4;
                split1(f.x, h4.x, l4.x); split1(f.y, h4.y, l4.y);
                split1(f.z, h4.z, l4.z); split1(f.w, h4.w, l4.w);
                *(ushort4*)&As_hi[ar * 32 + ac0 + 4 * q] = h4;
                *(ushort4*)&As_lo[ar * 32 + ac0 + 4 * q] = l4;
            }
        }
        #pragma unroll
        for (int g = tid; g < 512; g += 256) {
            int r = g >> 2, cs = (g & 3) * 8;
            size_t src = (size_t)(col0 + r) * ldBk + k0 + cs;
            ((uint4*)Bs_hi)[g] = *(const uint4*)&BeHi[src];
            ((uint4*)Bs_lo)[g] = *(const uint4*)&BeLo[src];
        }
        __syncthreads();
        f16x8 ah[4], al[4], bh[4], bl[4];
        #pragma unroll
        for (int i = 0; i < 4; i++) {
            int o = (wrow + 16 * i + m_) * 32 + q_ * 8;
            ah[i] = *(const f16x8*)&As_hi[o];
            al[i] = *(const f16x8*)&As_lo[o];
        }
        #pragma unroll
        for (int j = 0; j < 4; j++) {
            int o = (wcol + 16 * j + m_) * 32 + q_ * 8;
            bh[j] = *(const f16x8*)&Bs_hi[o];
            bl[j] = *(const f16x8*)&Bs_lo[o];
        }
        #pragma unroll
        for (int i = 0; i < 4; i++)
            #pragma unroll
            for (int j = 0; j < 4; j++) {
                acc[i][j] = __builtin_amdgcn_mfma_f32_16x16x32_f16(ah[i], bl[j], acc[i][j], 0, 0, 0);
                acc[i][j] = __builtin_amdgcn_mfma_f32_16x16x32_f16(al[i], bh[j], acc[i][j], 0, 0, 0);
                acc[i][j] = __builtin_amdgcn_mfma_f32_16x16x32_f16(ah[i], bh[j], acc[i][j], 0, 0, 0);
            }
        __syncthreads();
    }
    // C/D layout: col = lane&15, row = (lane>>4)*4 + reg  [validated r4]
    #pragma unroll
    for (int i = 0; i < 4; i++) {
        #pragma unroll
        for (int j = 0; j < 4; j++) {
            #pragma unroll
            for (int r = 0; r < 4; r++) {
                int gr = row0 + wrow + 16 * i + q_ * 4 + r;
                int gc = col0 + wcol + 16 * j + m_;
                float v = acc[i][j][r];
                size_t idx = (size_t)gr * ldc + gc;
                if (MODE == 0) {
                    C[idx] = v;
                } else if (MODE == 1) {
                    C[idx] = v + bias[gc] + resid[idx];
                } else if (MODE == 2) {
                    C[idx] = gelu_exact(v + bias[(size_t)e * biasStride + gc]);
                } else {
                    if (beta) v += C[idx];
                    C[idx] = v;
                }
            }
        }
    }
}

// ---------------- Layer-2 MoE bf16 MFMA GEMM (validated) ----------------
template<int MODE>
__global__ __launch_bounds__(256) void gemm_bt(
    const unsigned short* __restrict__ A, int ldA, int KLEN,
    const unsigned short* __restrict__ Bt, size_t BeStride,
    unsigned short* __restrict__ C, int ldc,
    const float* __restrict__ biasBase, int biasStride,
    const int* __restrict__ offs, const int* __restrict__ rowtok, int beta)
{
    __shared__ unsigned short As[128 * 32];
    __shared__ unsigned short Bs[128 * 32];
    __shared__ int rt[128];
    const int tid = threadIdx.x;
    const int row0 = blockIdx.y * 128, col0 = blockIdx.x * 128;
    int e = 0;
    #pragma unroll
    for (int i = 1; i < N_EXP; i++) if (offs[i] <= row0) e = i;
    if (MODE == 2) {
        for (int i = tid; i < 128; i += 256) rt[i] = rowtok[row0 + i];
        __syncthreads();
    }
    const unsigned short* Be = Bt + (size_t)e * BeStride;
    const int lane = tid & 63, w = tid >> 6;
    const int wrow = (w >> 1) * 64, wcol = (w & 1) * 64;
    const int m_ = lane & 15, q_ = lane >> 4;
    f32x4_t acc[4][4];
    #pragma unroll
    for (int i = 0; i < 4; i++)
        #pragma unroll
        for (int j = 0; j < 4; j++) acc[i][j] = (f32x4_t){0.f, 0.f, 0.f, 0.f};

    for (int k0 = 0; k0 < KLEN; k0 += 32) {
        #pragma unroll
        for (int g = tid; g < 512; g += 256) {
            int r = g >> 2, cs = (g & 3) * 8;
            uint4 val;
            if (MODE == 2) {
                int t = rt[r];
                val = (t >= 0) ? *(const uint4*)&A[(size_t)t * ldA + k0 + cs]
                               : make_uint4(0u, 0u, 0u, 0u);
            } else {
                val = *(const uint4*)&A[(size_t)(row0 + r) * ldA + k0 + cs];
            }
            ((uint4*)As)[g] = val;
        }
        #pragma unroll
        for (int g = tid; g < 512; g += 256) {
            int r = g >> 2, cs = (g & 3) * 8;
            ((uint4*)Bs)[g] = *(const uint4*)&Be[(size_t)(col0 + r) * KLEN + k0 + cs];
        }
        __syncthreads();
        bf16x8_t af[4], bfr[4];
        #pragma unroll
        for (int i = 0; i < 4; i++)
            af[i] = *(const bf16x8_t*)&As[(wrow + 16 * i + m_) * 32 + q_ * 8];
        #pragma unroll
        for (int j = 0; j < 4; j++)
            bfr[j] = *(const bf16x8_t*)&Bs[(wcol + 16 * j + m_) * 32 + q_ * 8];
        #pragma unroll
        for (int i = 0; i < 4; i++)
            #pragma unroll
            for (int j = 0; j < 4; j++)
                acc[i][j] = __builtin_amdgcn_mfma_f32_16x16x32_bf16(
                    af[i], bfr[j], acc[i][j], 0, 0, 0);
        __syncthreads();
    }
    #pragma unroll
    for (int i = 0; i < 4; i++) {
        #pragma unroll
        for (int j = 0; j < 4; j++) {
            #pragma unroll
            for (int r = 0; r < 4; r++) {
                int gr = row0 + wrow + 16 * i + q_ * 4 + r;
                int gc = col0 + wcol + 16 * j + m_;
                float v = acc[i][j][r];
                size_t idx = (size_t)gr * ldc + gc;
                if (MODE == 2) {
                    C[idx] = f2bf(gelu_exact(v + biasBase[(size_t)e * biasStride + gc]));
                } else {
                    if (beta) v += bf2f(C[idx]);
                    C[idx] = f2bf(v);
                }
            }
        }
    }
}

// ---------------- QKV prep: fp32 qkvb slab -> fp16 head-major Q (x0.125), K, V^T ----------------
// Qh/Kh: [B*H, S, 64] fp16 row-major; VTh: [B*H, 64, S] fp16 (d-major, s-contiguous).
__global__ __launch_bounds__(256) void qkv_prep(
    const float* __restrict__ qkvb, unsigned short* __restrict__ Qh,
    unsigned short* __restrict__ Kh, unsigned short* __restrict__ VTh)
{
    __shared__ float Ts[64][65];
    const int tid = threadIdx.x;
    const int t0 = blockIdx.x * 64, hh = blockIdx.y, b = blockIdx.z;
    const int bh = b * 8 + hh;
    const float* src = qkvb + ((size_t)(b * S_SEQ + t0)) * QKV_LD + hh * 64;
    #pragma unroll
    for (int i = 0; i < 4; i++) {
        int flat = tid + i * 256;
        int r = flat >> 4, c4 = (flat & 15) * 4;
        float4 qv = *(const float4*)&src[(size_t)r * QKV_LD + c4];
        float4 kv = *(const float4*)&src[(size_t)r * QKV_LD + 512 + c4];
        float4 vv = *(const float4*)&src[(size_t)r * QKV_LD + 1024 + c4];
        ushort4 qo, ko;
        qo.x = f2h(qv.x * 0.125f); qo.y = f2h(qv.y * 0.125f);
        qo.z = f2h(qv.z * 0.125f); qo.w = f2h(qv.w * 0.125f);
        ko.x = f2h(kv.x); ko.y = f2h(kv.y); ko.z = f2h(kv.z); ko.w = f2h(kv.w);
        size_t o = ((size_t)bh * S_SEQ + t0 + r) * 64 + c4;
        *(ushort4*)&Qh[o] = qo;
        *(ushort4*)&Kh[o] = ko;
        Ts[r][c4] = vv.x; Ts[r][c4 + 1] = vv.y; Ts[r][c4 + 2] = vv.z; Ts[r][c4 + 3] = vv.w;
    }
    __syncthreads();
    #pragma unroll
    for (int i = 0; i < 4; i++) {
        int flat = tid + i * 256;
        int d = flat >> 4, s4 = (flat & 15) * 4;
        ushort4 vo;
        vo.x = f2h(Ts[s4][d]);     vo.y = f2h(Ts[s4 + 1][d]);
        vo.z = f2h(Ts[s4 + 2][d]); vo.w = f2h(Ts[s4 + 3][d]);
        *(ushort4*)&VTh[((size_t)bh * 64 + d) * S_SEQ + t0 + s4] = vo;
    }
}

// ---------------- Flash attention, fp16 MFMA (fp32 softmax/accum) ----------------
// Frag layouts identical to validated gemm_f16x3:
//   A/B operand: row/col = lane&15, k-elems = (lane>>4)*8 .. +7 (contiguous)
//   C/D: col = lane&15, row = (lane>>4)*4 + reg
// Per block: 64 q-rows (wave w owns rows [16w,16w+16)), 16 KV steps of 64.
__global__ __launch_bounds__(256) void flash_attn_mfma(
    const unsigned short* __restrict__ Qh, const unsigned short* __restrict__ Kh,
    const unsigned short* __restrict__ VTh, float* __restrict__ out)
{
    __shared__ unsigned short Ks[64 * 72];   // K rows kv, d-contig, +8 pad
    __shared__ unsigned short Vt[64 * 72];   // V^T rows d, kv-contig, +8 pad
    __shared__ unsigned short Ps[64 * 72];   // P rows q, kv-contig, +8 pad
    const int tid = threadIdx.x;
    const int lane = tid & 63, w = tid >> 6;
    const int m_ = lane & 15, q_ = lane >> 4;
    const int hh = blockIdx.y, b = blockIdx.z;
    const int bh = b * 8 + hh;
    const int q0 = blockIdx.x * 64;
    const size_t qbase = ((size_t)bh * S_SEQ + q0) * 64;
    const size_t kbase = (size_t)bh * S_SEQ * 64;
    const size_t vbase = (size_t)bh * 64 * S_SEQ;

    f16x8 qa[2];
    #pragma unroll
    for (int c = 0; c < 2; c++)
        qa[c] = *(const f16x8*)&Qh[qbase + (size_t)(w * 16 + m_) * 64 + c * 32 + q_ * 8];

    float m_run[4], l_run[4];
    f32x4_t acc[4];
    #pragma unroll
    for (int r = 0; r < 4; r++) { m_run[r] = -INFINITY; l_run[r] = 0.0f; }
    #pragma unroll
    for (int oj = 0; oj < 4; oj++) acc[oj] = (f32x4_t){0.f, 0.f, 0.f, 0.f};

    for (int kv0 = 0; kv0 < S_SEQ; kv0 += 64) {
        __syncthreads();   // prior PV reads of Ks/Vt done before overwrite
        #pragma unroll
        for (int i = 0; i < 2; i++) {
            int g = tid + i * 256;
            int r = g >> 3, c8 = (g & 7) * 8;
            *(uint4*)&Ks[r * 72 + c8] =
                *(const uint4*)&Kh[kbase + (size_t)(kv0 + r) * 64 + c8];
            *(uint4*)&Vt[r * 72 + c8] =
                *(const uint4*)&VTh[vbase + (size_t)r * S_SEQ + kv0 + c8];
        }
        __syncthreads();
        // S = Q K^T  (fp32 frags); lane holds rows q_*4+r, col kv = 16j + m_
        f32x4_t s[4];
        #pragma unroll
        for (int j = 0; j < 4; j++) s[j] = (f32x4_t){0.f, 0.f, 0.f, 0.f};
        #pragma unroll
        for (int c = 0; c < 2; c++)
            #pragma unroll
            for (int j = 0; j < 4; j++) {
                f16x8 kb = *(const f16x8*)&Ks[(j * 16 + m_) * 72 + c * 32 + q_ * 8];
                s[j] = __builtin_amdgcn_mfma_f32_16x16x32_f16(qa[c], kb, s[j], 0, 0, 0);
            }
        // online softmax: reduce over j in-lane, over m_ via shfl_xor(1,2,4,8)
        float alpha[4];
        #pragma unroll
        for (int r = 0; r < 4; r++) {
            float rm = fmaxf(fmaxf(s[0][r], s[1][r]), fmaxf(s[2][r], s[3][r]));
            #pragma unroll
            for (int mk = 1; mk < 16; mk <<= 1)
                rm = fmaxf(rm, __shfl_xor(rm, mk));
            float mn = fmaxf(m_run[r], rm);
            alpha[r] = __expf(m_run[r] - mn);
            m_run[r] = mn;
            float ps = 0.0f;
            #pragma unroll
            for (int j = 0; j < 4; j++) {
                float p = __expf(s[j][r] - mn);
                s[j][r] = p;
                ps += p;
            }
            #pragma unroll
            for (int mk = 1; mk < 16; mk <<= 1)
                ps += __shfl_xor(ps, mk);
            l_run[r] = l_run[r] * alpha[r] + ps;
        }
        #pragma unroll
        for (int oj = 0; oj < 4; oj++)
            #pragma unroll
            for (int r = 0; r < 4; r++)
                acc[oj][r] *= alpha[r];
        // P -> LDS (fp16), rows q = 16w + q_*4 + r, col kv = 16j + m_
        #pragma unroll
        for (int j = 0; j < 4; j++)
            #pragma unroll
            for (int r = 0; r < 4; r++)
                Ps[(w * 16 + q_ * 4 + r) * 72 + j * 16 + m_] = f2h(s[j][r]);
        __syncthreads();
        // O += P V : A = P rows q (own 16 rows), B = V^T rows d
        #pragma unroll
        for (int c = 0; c < 2; c++) {
            f16x8 pa = *(const f16x8*)&Ps[(w * 16 + m_) * 72 + c * 32 + q_ * 8];
            #pragma unroll
            for (int oj = 0; oj < 4; oj++) {
                f16x8 vb = *(const f16x8*)&Vt[(oj * 16 + m_) * 72 + c * 32 + q_ * 8];
                acc[oj] = __builtin_amdgcn_mfma_f32_16x16x32_f16(pa, vb, acc[oj], 0, 0, 0);
            }
        }
    }
    const size_t obase = ((size_t)b * S_SEQ + q0) * D_MODEL + hh * 64;
    #pragma unroll
    for (int r = 0; r < 4; r++) {
        float inv = 1.0f / l_run[r];
        #pragma unroll
        for (int oj = 0; oj < 4; oj++)
            out[obase + (size_t)(w * 16 + q_ * 4 + r) * D_MODEL + oj * 16 + m_] =
                acc[oj][r] * inv;
    }
}

// ---------------- Gate (validated): reads fp32 h2 ----------------
__global__ __launch_bounds__(64) void gate_kernel(
    const float* __restrict__ h, const float* __restrict__ gw,
    int* __restrict__ topi, float* __restrict__ gates, int* __restrict__ counts)
{
    const int t = blockIdx.x, lane = threadIdx.x;
    const float* hr = h + (size_t)t * D_MODEL;
    float acc[N_EXP] = {};
    for (int d = lane; d < D_MODEL; d += 64) {
        float xv = hr[d];
        const float* g = gw + (size_t)d * N_EXP;
        #pragma unroll
        for (int e = 0; e < N_EXP; e++) acc[e] += xv * g[e];
    }
    __shared__ float red[64][N_EXP];
    #pragma unroll
    for (int e = 0; e < N_EXP; e++) red[lane][e] = acc[e];
    __syncthreads();
    __shared__ float logits[N_EXP];
    if (lane < N_EXP) {
        float s = 0.0f;
        for (int i = 0; i < 64; i++) s += red[i][lane];
        logits[lane] = s;
    }
    __syncthreads();
    if (lane == 0) {
        int e0 = 0; float v0 = logits[0];
        #pragma unroll
        for (int e = 1; e < N_EXP; e++) if (logits[e] > v0) { v0 = logits[e]; e0 = e; }
        int e1 = -1; float v1 = -INFINITY;
        #pragma unroll
        for (int e = 0; e < N_EXP; e++) if (e != e0 && logits[e] > v1) { v1 = logits[e]; e1 = e; }
        float g0 = 1.0f / (1.0f + __expf(v1 - v0));
        float g1 = 1.0f - g0;
        topi[2 * t] = e0; topi[2 * t + 1] = e1;
        gates[2 * t] = g0; gates[2 * t + 1] = g1;
        atomicAdd(&counts[e0], 1);
        atomicAdd(&counts[e1], 1);
    }
}

__global__ void offsets_kernel(const int* __restrict__ counts, int* __restrict__ offs)
{
    int off = 0;
    for (int e = 0; e < N_EXP; e++) {
        offs[e] = off;
        off += (counts[e] + 127) & ~127;
    }
    offs[N_EXP] = off;
}

__global__ void scatter_kernel(const int* __restrict__ topi, const int* __restrict__ offs,
                               int* __restrict__ fill, int* __restrict__ rowpos,
                               int* __restrict__ rowtok)
{
    int t = blockIdx.x * blockDim.x + threadIdx.x;
    if (t >= T_TOK) return;
    #pragma unroll
    for (int i = 0; i < 2; i++) {
        int e = topi[2 * t + i];
        int pos = atomicAdd(&fill[e], 1);
        int row = offs[e] + pos;
        rowpos[2 * t + i] = row;
        rowtok[row] = t;
    }
}

template<int YBF16>
__global__ __launch_bounds__(512) void combine_kernel(
    const float* __restrict__ x1, const void* __restrict__ y,
    const int* __restrict__ topi, const float* __restrict__ gates,
    const int* __restrict__ rowpos, const float* __restrict__ b2l,
    float* __restrict__ out)
{
    const int t = blockIdx.x, d = threadIdx.x;
    int e0 = topi[2 * t], e1 = topi[2 * t + 1];
    float g0 = gates[2 * t], g1 = gates[2 * t + 1];
    int r0 = rowpos[2 * t], r1 = rowpos[2 * t + 1];
    float y0, y1;
    if (YBF16) {
        const unsigned short* yp = (const unsigned short*)y;
        y0 = bf2f(yp[(size_t)r0 * D_MODEL + d]);
        y1 = bf2f(yp[(size_t)r1 * D_MODEL + d]);
    } else {
        const float* yp = (const float*)y;
        y0 = yp[(size_t)r0 * D_MODEL + d];
        y1 = yp[(size_t)r1 * D_MODEL + d];
    }
    out[(size_t)t * D_MODEL + d] = x1[(size_t)t * D_MODEL + d]
        + g0 * (y0 + b2l[(size_t)e0 * D_MODEL + d])
        + g1 * (y1 + b2l[(size_t)e1 * D_MODEL + d]);
}

extern "C" void kernel_launch(void* const* d_in, const int* in_sizes, int n_in,
                              void* d_out, int out_size, void* d_ws, size_t ws_size,
                              hipStream_t stream)
{
    const float* x0    = (const float*)d_in[0];
    const float* ln1w  = (const float*)d_in[1];
    const float* ln1b  = (const float*)d_in[2];
    const float* wq    = (const float*)d_in[3];
    const float* wk    = (const float*)d_in[4];
    const float* wv    = (const float*)d_in[5];
    const float* wo    = (const float*)d_in[6];
    const float* bo    = (const float*)d_in[7];
    const float* ln2w  = (const float*)d_in[8];
    const float* ln2b  = (const float*)d_in[9];
    const float* gatew = (const float*)d_in[10];
    const float* w1    = (const float*)d_in[11];
    const float* b1    = (const float*)d_in[12];
    const float* w2    = (const float*)d_in[13];
    const float* b2    = (const float*)d_in[14];
    float* out = (float*)d_out;

    // ---- Time-phased workspace, total ~47.2 MiB (R2/R4-proven budget <= ~49.8) ----
    // x1 [0,8) | H [8,16): h -> attn -> h2
    //   attention phase only: Qh [0,4), Kh [4,8)  (x1 is dead there), VTh [40,44)
    //   (VTh dead before wo tconv writes wT@43; dead before MoE hmid@34..43 is read)
    // [16,40): attn phase qkvb (24 MiB)
    //   L1 MoE: yb_f32 [16,34), hmid_f32 [34,43)
    //   L2 MoE: yb_bf16 [16,25), hmid_bf16 [25,29.5), h2b [30,34)
    // W [43,47): proj wT_hi@43 (1.5M), wT_lo@45 (1.5M)
    //            L1 chunks: w1T/w2T hi@43 (2M), lo@45 (2M)
    //            L2 chunks: w1Tc_bf@43 (1M), w2Tc_bf@45 (1M)
    // ints @47
    // x2 (inter-layer residual) := d_out  (safe: layer-1 combine never reads xin)
    char* ws = (char*)d_ws;
    const size_t MiB = 1 << 20;
    float* x1   = (float*)(ws + 0);
    float* h    = (float*)(ws + 8 * MiB);
    float* attn = (float*)(ws + 8 * MiB);
    float* h2   = (float*)(ws + 8 * MiB);
    float* qkvb = (float*)(ws + 16 * MiB);
    unsigned short* Qh  = (unsigned short*)(ws + 0);
    unsigned short* Kh  = (unsigned short*)(ws + 4 * MiB);
    unsigned short* VTh = (unsigned short*)(ws + 40 * MiB);
    float* yb_f32   = (float*)(ws + 16 * MiB);
    float* hmid_f32 = (float*)(ws + 34 * MiB);
    unsigned short* yb_bf16   = (unsigned short*)(ws + 16 * MiB);
    unsigned short* hmid_bf16 = (unsigned short*)(ws + 25 * MiB);
    unsigned short* h2b       = (unsigned short*)(ws + 30 * MiB);
    unsigned short* wT_hi     = (unsigned short*)(ws + 43 * MiB);
    unsigned short* wT_lo     = (unsigned short*)(ws + 45 * MiB);
    unsigned short* w1Tc_bf   = (unsigned short*)(ws + 43 * MiB);
    unsigned short* w2Tc_bf   = (unsigned short*)(ws + 45 * MiB);
    size_t oI = 47 * MiB;
    int*   topi   = (int*)(ws + oI);
    float* gates  = (float*)(ws + oI + 2 * T_TOK * 4);
    int*   rowpos = (int*)(ws + oI + 4 * T_TOK * 4);
    int*   rowtok = (int*)(ws + oI + 6 * T_TOK * 4);
    int*   meta   = (int*)(ws + oI + 6 * T_TOK * 4 + CAP * 4);
    int* counts = meta;
    int* fill   = meta + 8;
    int* offs   = meta + 16;
    float* x2 = out;   // inter-layer residual lives in d_out

    const dim3 t512(16, 16, 1);
    const dim3 tcW1(CHUNK / 32, 16, 8);   // w1 chunk [K=512, N=256]
    const dim3 tcW2(16, CHUNK / 32, 8);   // w2 chunk [K=256, N=512]
    const dim3 gQKV(QKV_LD / 128, T_TOK / 128);
    const dim3 gO(4, T_TOK / 128);
    const dim3 gUp(CHUNK / 128, CAP / 128);
    const dim3 gDn(4, CAP / 128);
    const dim3 gAttn(S_SEQ / 64, 8, 4);

    for (int l = 0; l < 2; l++) {
        const float* xin = (l == 0) ? x0 : x2;
        float* xout = (l == 1) ? out : x2;
        const float* wq_l = wq + (size_t)l * D_MODEL * D_MODEL;
        const float* wk_l = wk + (size_t)l * D_MODEL * D_MODEL;
        const float* wv_l = wv + (size_t)l * D_MODEL * D_MODEL;
        const float* wo_l = wo + (size_t)l * D_MODEL * D_MODEL;
        const float* w1_l = w1 + (size_t)l * N_EXP * D_MODEL * DH_FF;
        const float* w2_l = w2 + (size_t)l * N_EXP * DH_FF * D_MODEL;
        const float* b1_l = b1 + (size_t)l * N_EXP * DH_FF;

        ln_kernel<<<T_TOK, 256, 0, stream>>>(xin, ln1w + (size_t)l * D_MODEL,
                                             ln1b + (size_t)l * D_MODEL, h, nullptr);
        // fused QKV: wqkvT = [q|k|v] transposed+split, one MODE0 gemm N=1536
        tconv_split<<<t512, 256, 0, stream>>>(wq_l, D_MODEL, 0, wT_hi, wT_lo, D_MODEL, 0);
        tconv_split<<<t512, 256, 0, stream>>>(wk_l, D_MODEL, 0,
                                              wT_hi + 512 * 512, wT_lo + 512 * 512,
                                              D_MODEL, 0);
        tconv_split<<<t512, 256, 0, stream>>>(wv_l, D_MODEL, 0,
                                              wT_hi + 1024 * 512, wT_lo + 1024 * 512,
                                              D_MODEL, 0);
        gemm_f16x3<0><<<gQKV, 256, 0, stream>>>(h, D_MODEL, D_MODEL, wT_hi, wT_lo,
                                                D_MODEL, 0, qkvb, QKV_LD,
                                                nullptr, 0, nullptr, nullptr, nullptr, 0);
        qkv_prep<<<gAttn, 256, 0, stream>>>(qkvb, Qh, Kh, VTh);
        flash_attn_mfma<<<gAttn, 256, 0, stream>>>(Qh, Kh, VTh, attn);
        tconv_split<<<t512, 256, 0, stream>>>(wo_l, D_MODEL, 0, wT_hi, wT_lo, D_MODEL, 0);
        gemm_f16x3<1><<<gO, 256, 0, stream>>>(attn, D_MODEL, D_MODEL, wT_hi, wT_lo,
                                              D_MODEL, 0, x1, D_MODEL,
                                              bo + (size_t)l * D_MODEL, 0, xin,
                                              nullptr, nullptr, 0);
        ln_kernel<<<T_TOK, 256, 0, stream>>>(x1, ln2w + (size_t)l * D_MODEL,
                                             ln2b + (size_t)l * D_MODEL, h2,
                                             (l == 1) ? h2b : nullptr);

        hipMemsetAsync(meta, 0, 64, stream);
        hipMemsetAsync(rowtok, 0xFF, CAP * 4, stream);
        gate_kernel<<<T_TOK, 64, 0, stream>>>(h2, gatew + (size_t)l * D_MODEL * N_EXP,
                                              topi, gates, counts);
        offsets_kernel<<<1, 1, 0, stream>>>(counts, offs);
        scatter_kernel<<<16, 256, 0, stream>>>(topi, offs, fill, rowpos, rowtok);

        if (l == 0) {
            // fp16x3 MoE: fp32-grade -> keeps L2 routing faithful
            for (int c = 0; c < DH_FF / CHUNK; c++) {
                const float* w1c = w1_l + (size_t)c * CHUNK;
                const float* b1c = b1_l + (size_t)c * CHUNK;
                const float* w2c = w2_l + (size_t)c * CHUNK * D_MODEL;
                tconv_split<<<tcW1, 256, 0, stream>>>(w1c, DH_FF, (size_t)D_MODEL * DH_FF,
                                                      wT_hi, wT_lo, D_MODEL,
                                                      (size_t)CHUNK * D_MODEL);
                gemm_f16x3<2><<<gUp, 256, 0, stream>>>(h2, D_MODEL, D_MODEL,
                                                       wT_hi, wT_lo, D_MODEL,
                                                       (size_t)CHUNK * D_MODEL,
                                                       hmid_f32, CHUNK, b1c, DH_FF,
                                                       nullptr, offs, rowtok, 0);
                tconv_split<<<tcW2, 256, 0, stream>>>(w2c, D_MODEL, (size_t)DH_FF * D_MODEL,
                                                      wT_hi, wT_lo, CHUNK,
                                                      (size_t)D_MODEL * CHUNK);
                gemm_f16x3<3><<<gDn, 256, 0, stream>>>(hmid_f32, CHUNK, CHUNK,
                                                       wT_hi, wT_lo, CHUNK,
                                                       (size_t)D_MODEL * CHUNK,
                                                       yb_f32, D_MODEL, nullptr, 0,
                                                       nullptr, offs, nullptr,
                                                       (c > 0) ? 1 : 0);
            }
            combine_kernel<0><<<T_TOK, 512, 0, stream>>>(
                x1, yb_f32, topi, gates, rowpos,
                b2 + (size_t)l * N_EXP * D_MODEL, xout);
        } else {
            // bf16 MoE (validated): post-final-gate, error only reaches output
            for (int c = 0; c < DH_FF / CHUNK; c++) {
                const float* w1c = w1_l + (size_t)c * CHUNK;
                const float* b1c = b1_l + (size_t)c * CHUNK;
                const float* w2c = w2_l + (size_t)c * CHUNK * D_MODEL;
                tconv<<<tcW1, 256, 0, stream>>>(w1c, DH_FF, (size_t)D_MODEL * DH_FF,
                                                w1Tc_bf, D_MODEL, (size_t)CHUNK * D_MODEL);
                gemm_bt<2><<<gUp, 256, 0, stream>>>(h2b, D_MODEL, D_MODEL,
                                                    w1Tc_bf, (size_t)CHUNK * D_MODEL,
                                                    hmid_bf16, CHUNK, b1c, DH_FF,
                                                    offs, rowtok, 0);
                tconv<<<tcW2, 256, 0, stream>>>(w2c, D_MODEL, (size_t)DH_FF * D_MODEL,
                                                w2Tc_bf, CHUNK, (size_t)D_MODEL * CHUNK);
                gemm_bt<3><<<gDn, 256, 0, stream>>>(hmid_bf16, CHUNK, CHUNK,
                                                    w2Tc_bf, (size_t)D_MODEL * CHUNK,
                                                    yb_bf16, D_MODEL, nullptr, 0,
                                                    offs, nullptr, (c > 0) ? 1 : 0);
            }
            combine_kernel<1><<<T_TOK, 512, 0, stream>>>(
                x1, yb_bf16, topi, gates, rowpos,
                b2 + (size_t)l * N_EXP * D_MODEL, xout);
        }
    }
}

// Round 2
// 1726.745 us; speedup vs baseline: 1.2211x; 1.0885x over previous
//
#include <hip/hip_runtime.h>
#include <cmath>

#define D_MODEL 512
#define T_TOK   4096
#define S_SEQ   1024
#define DH_FF   2048
#define N_EXP   8
#define CAP     9216    // 8192 assignments + 8*127 pad, 128-aligned
#define CHUNK   256     // MoE hidden-dim chunk
#define QKV_LD  1536

typedef __attribute__((ext_vector_type(8))) short bf16x8_t;
typedef __attribute__((ext_vector_type(4))) float f32x4_t;
typedef _Float16 f16x8 __attribute__((ext_vector_type(8)));

__device__ __forceinline__ float gelu_exact(float x) {
    return 0.5f * x * (1.0f + erff(x * 0.70710678118654752440f));
}
__device__ __forceinline__ unsigned short f2bf(float f) {
    union { float f; unsigned int u; } v; v.f = f;
    unsigned int r = v.u + 0x7fff + ((v.u >> 16) & 1);   // RNE
    return (unsigned short)(r >> 16);
}
__device__ __forceinline__ float bf2f(unsigned short u) {
    union { unsigned int i; float f; } v; v.i = ((unsigned int)u) << 16; return v.f;
}
__device__ __forceinline__ unsigned short f2h(float f) {
    _Float16 h = (_Float16)f;
    return __builtin_bit_cast(unsigned short, h);
}
// fp32 -> fp16 hi + fp16 lo (Ootomo split): v ~= hi + lo, rel err ~2^-22
__device__ __forceinline__ void split1(float v, unsigned short& h, unsigned short& l) {
    _Float16 hf = (_Float16)v;
    _Float16 lf = (_Float16)(v - (float)hf);
    h = __builtin_bit_cast(unsigned short, hf);
    l = __builtin_bit_cast(unsigned short, lf);
}

// ---------------- LayerNorm: fp32 in -> fp32 out (+ optional bf16 copy) ----------------
__global__ __launch_bounds__(256) void ln_kernel(
    const float* __restrict__ x, const float* __restrict__ w,
    const float* __restrict__ b, float* __restrict__ out,
    unsigned short* __restrict__ outb)
{
    const int t = blockIdx.x, tid = threadIdx.x;
    const float* xr = x + (size_t)t * D_MODEL;
    float v0 = xr[tid], v1 = xr[tid + 256];
    __shared__ float ss[256], sq[256];
    ss[tid] = v0 + v1;
    sq[tid] = v0 * v0 + v1 * v1;
    __syncthreads();
    for (int st = 128; st > 0; st >>= 1) {
        if (tid < st) { ss[tid] += ss[tid + st]; sq[tid] += sq[tid + st]; }
        __syncthreads();
    }
    float mu  = ss[0] * (1.0f / 512.0f);
    float var = sq[0] * (1.0f / 512.0f) - mu * mu;
    float rs  = rsqrtf(var + 1e-6f);
    float o0 = (v0 - mu) * rs * w[tid]       + b[tid];
    float o1 = (v1 - mu) * rs * w[tid + 256] + b[tid + 256];
    float* outr = out + (size_t)t * D_MODEL;
    outr[tid] = o0; outr[tid + 256] = o1;
    if (outb) {
        unsigned short* ob = outb + (size_t)t * D_MODEL;
        ob[tid] = f2bf(o0); ob[tid + 256] = f2bf(o1);
    }
}

// ------- Transpose-split: fp32 [K,N] slab -> fp16 hi[N,K] + lo[N,K] -------
__global__ __launch_bounds__(256) void tconv_split(
    const float* __restrict__ in, int inLd, size_t eStrideIn,
    unsigned short* __restrict__ outHi, unsigned short* __restrict__ outLo,
    int outLd, size_t eStrideOut)
{
    __shared__ float Ts[32][33];
    const int tid = threadIdx.x;
    const int k0 = blockIdx.y * 32, n0 = blockIdx.x * 32;
    in    += (size_t)blockIdx.z * eStrideIn;
    outHi += (size_t)blockIdx.z * eStrideOut;
    outLo += (size_t)blockIdx.z * eStrideOut;
    int r = tid >> 3, c = (tid & 7) * 4;
    float4 v = *(const float4*)&in[(size_t)(k0 + r) * inLd + n0 + c];
    Ts[r][c] = v.x; Ts[r][c + 1] = v.y; Ts[r][c + 2] = v.z; Ts[r][c + 3] = v.w;
    __syncthreads();
    int n = tid >> 3, kk = (tid & 7) * 4;
    ushort4 h4, l4;
    split1(Ts[kk][n],     h4.x, l4.x); split1(Ts[kk + 1][n], h4.y, l4.y);
    split1(Ts[kk + 2][n], h4.z, l4.z); split1(Ts[kk + 3][n], h4.w, l4.w);
    size_t o = (size_t)(n0 + n) * outLd + k0 + kk;
    *(ushort4*)&outHi[o] = h4;
    *(ushort4*)&outLo[o] = l4;
}

// ------- Transpose-convert bf16 (validated, L2 MoE) -------
__global__ __launch_bounds__(256) void tconv(
    const float* __restrict__ in, int inLd, size_t eStrideIn,
    unsigned short* __restrict__ out, int outLd, size_t eStrideOut)
{
    __shared__ float Ts[32][33];
    const int tid = threadIdx.x;
    const int k0 = blockIdx.y * 32, n0 = blockIdx.x * 32;
    in  += (size_t)blockIdx.z * eStrideIn;
    out += (size_t)blockIdx.z * eStrideOut;
    int r = tid >> 3, c = (tid & 7) * 4;
    float4 v = *(const float4*)&in[(size_t)(k0 + r) * inLd + n0 + c];
    Ts[r][c] = v.x; Ts[r][c + 1] = v.y; Ts[r][c + 2] = v.z; Ts[r][c + 3] = v.w;
    __syncthreads();
    int n = tid >> 3, kk = (tid & 7) * 4;
    ushort4 o;
    o.x = f2bf(Ts[kk][n]);     o.y = f2bf(Ts[kk + 1][n]);
    o.z = f2bf(Ts[kk + 2][n]); o.w = f2bf(Ts[kk + 3][n]);
    *(ushort4*)&out[(size_t)(n0 + n) * outLd + k0 + kk] = o;
}

// ---------------- fp16x3 MFMA GEMM (fp32-grade accuracy), 128x128 tiles ----------------
// A fp32 row-major (split on the fly); Bt pre-split fp16 hi/lo, [N][K] K-contiguous.
// MODE 0: C fp32 = acc                 (qkv proj, ldc=1536)
// MODE 1: C fp32 = acc + bias + resid  (o proj)
// MODE 2: C fp32 = gelu(acc+bias_e), A gathered via rowtok (MoE up)
// MODE 3: C fp32 (+)= acc              (MoE down, per-expert B)
template<int MODE>
__global__ __launch_bounds__(256) void gemm_f16x3(
    const float* __restrict__ A, int lda, int KLEN,
    const unsigned short* __restrict__ BtHi, const unsigned short* __restrict__ BtLo,
    int ldBk, size_t BeStride,
    float* __restrict__ C, int ldc,
    const float* __restrict__ bias, int biasStride,
    const float* __restrict__ resid,
    const int* __restrict__ offs, const int* __restrict__ rowtok, int beta)
{
    __shared__ unsigned short As_hi[128 * 32], As_lo[128 * 32];
    __shared__ unsigned short Bs_hi[128 * 32], Bs_lo[128 * 32];
    __shared__ int rt[128];
    const int tid = threadIdx.x;
    const int row0 = blockIdx.y * 128, col0 = blockIdx.x * 128;
    int e = 0;
    if (MODE >= 2) {
        #pragma unroll
        for (int i = 1; i < N_EXP; i++) if (offs[i] <= row0) e = i;
    }
    if (MODE == 2) {
        for (int i = tid; i < 128; i += 256) rt[i] = rowtok[row0 + i];
        __syncthreads();
    }
    const unsigned short* BeHi = BtHi + (size_t)e * BeStride;
    const unsigned short* BeLo = BtLo + (size_t)e * BeStride;
    const int lane = tid & 63, w = tid >> 6;
    const int wrow = (w >> 1) * 64, wcol = (w & 1) * 64;
    const int m_ = lane & 15, q_ = lane >> 4;
    f32x4_t acc[4][4];
    #pragma unroll
    for (int i = 0; i < 4; i++)
        #pragma unroll
        for (int j = 0; j < 4; j++) acc[i][j] = (f32x4_t){0.f, 0.f, 0.f, 0.f};

    const int ar = tid >> 1, ac0 = (tid & 1) * 16;
    for (int k0 = 0; k0 < KLEN; k0 += 32) {
        {
            const float* Arow;
            bool zero = false;
            if (MODE == 2) {
                int t = rt[ar];
                zero = (t < 0);
                Arow = A + (size_t)(zero ? 0 : t) * lda;
            } else {
                Arow = A + (size_t)(row0 + ar) * lda;
            }
            #pragma unroll
            for (int q = 0; q < 4; q++) {
                float4 f = zero ? make_float4(0.f, 0.f, 0.f, 0.f)
                                : *(const float4*)&Arow[k0 + ac0 + 4 * q];
                ushort4 h4, l4;
                split1(f.x, h4.x, l4.x); split1(f.y, h4.y, l4.y);
                split1(f.z, h4.z, l4.z); split1(f.w, h4.w, l4.w);
                *(ushort4*)&As_hi[ar * 32 + ac0 + 4 * q] = h4;
                *(ushort4*)&As_lo[ar * 32 + ac0 + 4 * q] = l4;
            }
        }
        #pragma unroll
        for (int g = tid; g < 512; g += 256) {
            int r = g >> 2, cs = (g & 3) * 8;
            size_t src = (size_t)(col0 + r) * ldBk + k0 + cs;
            ((uint4*)Bs_hi)[g] = *(const uint4*)&BeHi[src];
            ((uint4*)Bs_lo)[g] = *(const uint4*)&BeLo[src];
        }
        __syncthreads();
        f16x8 ah[4], al[4], bh[4], bl[4];
        #pragma unroll
        for (int i = 0; i < 4; i++) {
            int o = (wrow + 16 * i + m_) * 32 + q_ * 8;
            ah[i] = *(const f16x8*)&As_hi[o];
            al[i] = *(const f16x8*)&As_lo[o];
        }
        #pragma unroll
        for (int j = 0; j < 4; j++) {
            int o = (wcol + 16 * j + m_) * 32 + q_ * 8;
            bh[j] = *(const f16x8*)&Bs_hi[o];
            bl[j] = *(const f16x8*)&Bs_lo[o];
        }
        #pragma unroll
        for (int i = 0; i < 4; i++)
            #pragma unroll
            for (int j = 0; j < 4; j++) {
                acc[i][j] = __builtin_amdgcn_mfma_f32_16x16x32_f16(ah[i], bl[j], acc[i][j], 0, 0, 0);
                acc[i][j] = __builtin_amdgcn_mfma_f32_16x16x32_f16(al[i], bh[j], acc[i][j], 0, 0, 0);
                acc[i][j] = __builtin_amdgcn_mfma_f32_16x16x32_f16(ah[i], bh[j], acc[i][j], 0, 0, 0);
            }
        __syncthreads();
    }
    // C/D layout: col = lane&15, row = (lane>>4)*4 + reg  [validated r4]
    #pragma unroll
    for (int i = 0; i < 4; i++) {
        #pragma unroll
        for (int j = 0; j < 4; j++) {
            #pragma unroll
            for (int r = 0; r < 4; r++) {
                int gr = row0 + wrow + 16 * i + q_ * 4 + r;
                int gc = col0 + wcol + 16 * j + m_;
                float v = acc[i][j][r];
                size_t idx = (size_t)gr * ldc + gc;
                if (MODE == 0) {
                    C[idx] = v;
                } else if (MODE == 1) {
                    C[idx] = v + bias[gc] + resid[idx];
                } else if (MODE == 2) {
                    C[idx] = gelu_exact(v + bias[(size_t)e * biasStride + gc]);
                } else {
                    if (beta) v += C[idx];
                    C[idx] = v;
                }
            }
        }
    }
}

// ---------------- Layer-2 MoE bf16 MFMA GEMM (validated) ----------------
template<int MODE>
__global__ __launch_bounds__(256) void gemm_bt(
    const unsigned short* __restrict__ A, int ldA, int KLEN,
    const unsigned short* __restrict__ Bt, size_t BeStride,
    unsigned short* __restrict__ C, int ldc,
    const float* __restrict__ biasBase, int biasStride,
    const int* __restrict__ offs, const int* __restrict__ rowtok, int beta)
{
    __shared__ unsigned short As[128 * 32];
    __shared__ unsigned short Bs[128 * 32];
    __shared__ int rt[128];
    const int tid = threadIdx.x;
    const int row0 = blockIdx.y * 128, col0 = blockIdx.x * 128;
    int e = 0;
    #pragma unroll
    for (int i = 1; i < N_EXP; i++) if (offs[i] <= row0) e = i;
    if (MODE == 2) {
        for (int i = tid; i < 128; i += 256) rt[i] = rowtok[row0 + i];
        __syncthreads();
    }
    const unsigned short* Be = Bt + (size_t)e * BeStride;
    const int lane = tid & 63, w = tid >> 6;
    const int wrow = (w >> 1) * 64, wcol = (w & 1) * 64;
    const int m_ = lane & 15, q_ = lane >> 4;
    f32x4_t acc[4][4];
    #pragma unroll
    for (int i = 0; i < 4; i++)
        #pragma unroll
        for (int j = 0; j < 4; j++) acc[i][j] = (f32x4_t){0.f, 0.f, 0.f, 0.f};

    for (int k0 = 0; k0 < KLEN; k0 += 32) {
        #pragma unroll
        for (int g = tid; g < 512; g += 256) {
            int r = g >> 2, cs = (g & 3) * 8;
            uint4 val;
            if (MODE == 2) {
                int t = rt[r];
                val = (t >= 0) ? *(const uint4*)&A[(size_t)t * ldA + k0 + cs]
                               : make_uint4(0u, 0u, 0u, 0u);
            } else {
                val = *(const uint4*)&A[(size_t)(row0 + r) * ldA + k0 + cs];
            }
            ((uint4*)As)[g] = val;
        }
        #pragma unroll
        for (int g = tid; g < 512; g += 256) {
            int r = g >> 2, cs = (g & 3) * 8;
            ((uint4*)Bs)[g] = *(const uint4*)&Be[(size_t)(col0 + r) * KLEN + k0 + cs];
        }
        __syncthreads();
        bf16x8_t af[4], bfr[4];
        #pragma unroll
        for (int i = 0; i < 4; i++)
            af[i] = *(const bf16x8_t*)&As[(wrow + 16 * i + m_) * 32 + q_ * 8];
        #pragma unroll
        for (int j = 0; j < 4; j++)
            bfr[j] = *(const bf16x8_t*)&Bs[(wcol + 16 * j + m_) * 32 + q_ * 8];
        #pragma unroll
        for (int i = 0; i < 4; i++)
            #pragma unroll
            for (int j = 0; j < 4; j++)
                acc[i][j] = __builtin_amdgcn_mfma_f32_16x16x32_bf16(
                    af[i], bfr[j], acc[i][j], 0, 0, 0);
        __syncthreads();
    }
    #pragma unroll
    for (int i = 0; i < 4; i++) {
        #pragma unroll
        for (int j = 0; j < 4; j++) {
            #pragma unroll
            for (int r = 0; r < 4; r++) {
                int gr = row0 + wrow + 16 * i + q_ * 4 + r;
                int gc = col0 + wcol + 16 * j + m_;
                float v = acc[i][j][r];
                size_t idx = (size_t)gr * ldc + gc;
                if (MODE == 2) {
                    C[idx] = f2bf(gelu_exact(v + biasBase[(size_t)e * biasStride + gc]));
                } else {
                    if (beta) v += bf2f(C[idx]);
                    C[idx] = f2bf(v);
                }
            }
        }
    }
}

// ---------------- QKV prep: fp32 qkvb slab -> fp16 head-major Q (x0.125), K, V^T ----------------
// Qh/Kh: [B*H, S, 64] fp16 row-major; VTh: [B*H, 64, S] fp16 (d-major, s-contiguous).
__global__ __launch_bounds__(256) void qkv_prep(
    const float* __restrict__ qkvb, unsigned short* __restrict__ Qh,
    unsigned short* __restrict__ Kh, unsigned short* __restrict__ VTh)
{
    __shared__ float Ts[64][65];
    const int tid = threadIdx.x;
    const int t0 = blockIdx.x * 64, hh = blockIdx.y, b = blockIdx.z;
    const int bh = b * 8 + hh;
    const float* src = qkvb + ((size_t)(b * S_SEQ + t0)) * QKV_LD + hh * 64;
    #pragma unroll
    for (int i = 0; i < 4; i++) {
        int flat = tid + i * 256;
        int r = flat >> 4, c4 = (flat & 15) * 4;
        float4 qv = *(const float4*)&src[(size_t)r * QKV_LD + c4];
        float4 kv = *(const float4*)&src[(size_t)r * QKV_LD + 512 + c4];
        float4 vv = *(const float4*)&src[(size_t)r * QKV_LD + 1024 + c4];
        ushort4 qo, ko;
        qo.x = f2h(qv.x * 0.125f); qo.y = f2h(qv.y * 0.125f);
        qo.z = f2h(qv.z * 0.125f); qo.w = f2h(qv.w * 0.125f);
        ko.x = f2h(kv.x); ko.y = f2h(kv.y); ko.z = f2h(kv.z); ko.w = f2h(kv.w);
        size_t o = ((size_t)bh * S_SEQ + t0 + r) * 64 + c4;
        *(ushort4*)&Qh[o] = qo;
        *(ushort4*)&Kh[o] = ko;
        Ts[r][c4] = vv.x; Ts[r][c4 + 1] = vv.y; Ts[r][c4 + 2] = vv.z; Ts[r][c4 + 3] = vv.w;
    }
    __syncthreads();
    #pragma unroll
    for (int i = 0; i < 4; i++) {
        int flat = tid + i * 256;
        int d = flat >> 4, s4 = (flat & 15) * 4;
        ushort4 vo;
        vo.x = f2h(Ts[s4][d]);     vo.y = f2h(Ts[s4 + 1][d]);
        vo.z = f2h(Ts[s4 + 2][d]); vo.w = f2h(Ts[s4 + 3][d]);
        *(ushort4*)&VTh[((size_t)bh * 64 + d) * S_SEQ + t0 + s4] = vo;
    }
}

// ---------------- Flash attention, fp16 MFMA (fp32 softmax/accum) ----------------
// Frag layouts identical to validated gemm_f16x3:
//   A/B operand: row/col = lane&15, k-elems = (lane>>4)*8 .. +7 (contiguous)
//   C/D: col = lane&15, row = (lane>>4)*4 + reg
// Per block: 64 q-rows (wave w owns rows [16w,16w+16)), 16 KV steps of 64.
__global__ __launch_bounds__(256) void flash_attn_mfma(
    const unsigned short* __restrict__ Qh, const unsigned short* __restrict__ Kh,
    const unsigned short* __restrict__ VTh, float* __restrict__ out)
{
    __shared__ unsigned short Ks[64 * 72];   // K rows kv, d-contig, +8 pad
    __shared__ unsigned short Vt[64 * 72];   // V^T rows d, kv-contig, +8 pad
    __shared__ unsigned short Ps[64 * 72];   // P rows q, kv-contig, +8 pad
    const int tid = threadIdx.x;
    const int lane = tid & 63, w = tid >> 6;
    const int m_ = lane & 15, q_ = lane >> 4;
    const int hh = blockIdx.y, b = blockIdx.z;
    const int bh = b * 8 + hh;
    const int q0 = blockIdx.x * 64;
    const size_t qbase = ((size_t)bh * S_SEQ + q0) * 64;
    const size_t kbase = (size_t)bh * S_SEQ * 64;
    const size_t vbase = (size_t)bh * 64 * S_SEQ;

    f16x8 qa[2];
    #pragma unroll
    for (int c = 0; c < 2; c++)
        qa[c] = *(const f16x8*)&Qh[qbase + (size_t)(w * 16 + m_) * 64 + c * 32 + q_ * 8];

    float m_run[4], l_run[4];
    f32x4_t acc[4];
    #pragma unroll
    for (int r = 0; r < 4; r++) { m_run[r] = -INFINITY; l_run[r] = 0.0f; }
    #pragma unroll
    for (int oj = 0; oj < 4; oj++) acc[oj] = (f32x4_t){0.f, 0.f, 0.f, 0.f};

    for (int kv0 = 0; kv0 < S_SEQ; kv0 += 64) {
        __syncthreads();   // prior PV reads of Ks/Vt done before overwrite
        #pragma unroll
        for (int i = 0; i < 2; i++) {
            int g = tid + i * 256;
            int r = g >> 3, c8 = (g & 7) * 8;
            *(uint4*)&Ks[r * 72 + c8] =
                *(const uint4*)&Kh[kbase + (size_t)(kv0 + r) * 64 + c8];
            *(uint4*)&Vt[r * 72 + c8] =
                *(const uint4*)&VTh[vbase + (size_t)r * S_SEQ + kv0 + c8];
        }
        __syncthreads();
        // S = Q K^T  (fp32 frags); lane holds rows q_*4+r, col kv = 16j + m_
        f32x4_t s[4];
        #pragma unroll
        for (int j = 0; j < 4; j++) s[j] = (f32x4_t){0.f, 0.f, 0.f, 0.f};
        #pragma unroll
        for (int c = 0; c < 2; c++)
            #pragma unroll
            for (int j = 0; j < 4; j++) {
                f16x8 kb = *(const f16x8*)&Ks[(j * 16 + m_) * 72 + c * 32 + q_ * 8];
                s[j] = __builtin_amdgcn_mfma_f32_16x16x32_f16(qa[c], kb, s[j], 0, 0, 0);
            }
        // online softmax: reduce over j in-lane, over m_ via shfl_xor(1,2,4,8)
        float alpha[4];
        #pragma unroll
        for (int r = 0; r < 4; r++) {
            float rm = fmaxf(fmaxf(s[0][r], s[1][r]), fmaxf(s[2][r], s[3][r]));
            #pragma unroll
            for (int mk = 1; mk < 16; mk <<= 1)
                rm = fmaxf(rm, __shfl_xor(rm, mk));
            float mn = fmaxf(m_run[r], rm);
            alpha[r] = __expf(m_run[r] - mn);
            m_run[r] = mn;
            float ps = 0.0f;
            #pragma unroll
            for (int j = 0; j < 4; j++) {
                float p = __expf(s[j][r] - mn);
                s[j][r] = p;
                ps += p;
            }
            #pragma unroll
            for (int mk = 1; mk < 16; mk <<= 1)
                ps += __shfl_xor(ps, mk);
            l_run[r] = l_run[r] * alpha[r] + ps;
        }
        #pragma unroll
        for (int oj = 0; oj < 4; oj++)
            #pragma unroll
            for (int r = 0; r < 4; r++)
                acc[oj][r] *= alpha[r];
        // P -> LDS (fp16), rows q = 16w + q_*4 + r, col kv = 16j + m_
        #pragma unroll
        for (int j = 0; j < 4; j++)
            #pragma unroll
            for (int r = 0; r < 4; r++)
                Ps[(w * 16 + q_ * 4 + r) * 72 + j * 16 + m_] = f2h(s[j][r]);
        __syncthreads();
        // O += P V : A = P rows q (own 16 rows), B = V^T rows d
        #pragma unroll
        for (int c = 0; c < 2; c++) {
            f16x8 pa = *(const f16x8*)&Ps[(w * 16 + m_) * 72 + c * 32 + q_ * 8];
            #pragma unroll
            for (int oj = 0; oj < 4; oj++) {
                f16x8 vb = *(const f16x8*)&Vt[(oj * 16 + m_) * 72 + c * 32 + q_ * 8];
                acc[oj] = __builtin_amdgcn_mfma_f32_16x16x32_f16(pa, vb, acc[oj], 0, 0, 0);
            }
        }
    }
    const size_t obase = ((size_t)b * S_SEQ + q0) * D_MODEL + hh * 64;
    #pragma unroll
    for (int r = 0; r < 4; r++) {
        float inv = 1.0f / l_run[r];
        #pragma unroll
        for (int oj = 0; oj < 4; oj++)
            out[obase + (size_t)(w * 16 + q_ * 4 + r) * D_MODEL + oj * 16 + m_] =
                acc[oj][r] * inv;
    }
}

// ---------------- Gate: 4 tokens/block, pure shuffle reduce, NO atomics ----------------
__global__ __launch_bounds__(256) void gate_kernel(
    const float* __restrict__ h, const float* __restrict__ gw,
    int* __restrict__ topi, float* __restrict__ gates)
{
    const int w = threadIdx.x >> 6, lane = threadIdx.x & 63;
    const int t = blockIdx.x * 4 + w;
    const float* hr = h + (size_t)t * D_MODEL;
    float acc[N_EXP] = {};
    for (int d = lane; d < D_MODEL; d += 64) {
        float xv = hr[d];
        const float4 g0 = *(const float4*)&gw[(size_t)d * N_EXP];
        const float4 g1 = *(const float4*)&gw[(size_t)d * N_EXP + 4];
        acc[0] += xv * g0.x; acc[1] += xv * g0.y;
        acc[2] += xv * g0.z; acc[3] += xv * g0.w;
        acc[4] += xv * g1.x; acc[5] += xv * g1.y;
        acc[6] += xv * g1.z; acc[7] += xv * g1.w;
    }
    #pragma unroll
    for (int mk = 1; mk < 64; mk <<= 1) {
        #pragma unroll
        for (int e = 0; e < N_EXP; e++) acc[e] += __shfl_xor(acc[e], mk);
    }
    if (lane == 0) {
        int e0 = 0; float v0 = acc[0];
        #pragma unroll
        for (int e = 1; e < N_EXP; e++) if (acc[e] > v0) { v0 = acc[e]; e0 = e; }
        int e1 = -1; float v1 = -INFINITY;
        #pragma unroll
        for (int e = 0; e < N_EXP; e++) if (e != e0 && acc[e] > v1) { v1 = acc[e]; e1 = e; }
        float g0 = 1.0f / (1.0f + __expf(v1 - v0));
        float g1 = 1.0f - g0;
        topi[2 * t] = e0; topi[2 * t + 1] = e1;
        gates[2 * t] = g0; gates[2 * t + 1] = g1;
    }
}

// ---------------- Route: single block, ballot-based histogram + scatter, NO atomics ----------------
// 1024 threads = 16 waves; wave w owns assignments [w*512, (w+1)*512).
__global__ __launch_bounds__(1024) void route_kernel(
    const int* __restrict__ topi, int* __restrict__ offs,
    int* __restrict__ rowpos, int* __restrict__ rowtok)
{
    __shared__ int wcnt[16][N_EXP];
    __shared__ int wbase[16][N_EXP];
    __shared__ int offs_s[N_EXP + 1];
    const int tid = threadIdx.x, w = tid >> 6, lane = tid & 63;
    const unsigned long long lt = (1ULL << lane) - 1ULL;

    int mye[8];
    int cnt[N_EXP] = {};
    #pragma unroll
    for (int r = 0; r < 8; r++) {
        int i = w * 512 + r * 64 + lane;
        int e = topi[i];
        mye[r] = e;
        #pragma unroll
        for (int e8 = 0; e8 < N_EXP; e8++) {
            unsigned long long m = __ballot(e == e8);
            cnt[e8] += (int)__popcll(m);
        }
    }
    if (lane == 0) {
        #pragma unroll
        for (int e8 = 0; e8 < N_EXP; e8++) wcnt[w][e8] = cnt[e8];
    }
    __syncthreads();
    if (tid == 0) {
        int off = 0;
        for (int e8 = 0; e8 < N_EXP; e8++) {
            offs_s[e8] = off;
            int c = 0;
            for (int ww = 0; ww < 16; ww++) c += wcnt[ww][e8];
            off += (c + 127) & ~127;
        }
        offs_s[N_EXP] = off;
        for (int e8 = 0; e8 <= N_EXP; e8++) offs[e8] = offs_s[e8];
    }
    __syncthreads();
    if (tid < 128) {
        int ww = tid >> 3, e8 = tid & 7;
        int bse = offs_s[e8];
        for (int w2 = 0; w2 < ww; w2++) bse += wcnt[w2][e8];
        wbase[ww][e8] = bse;
    }
    __syncthreads();
    int base[N_EXP];
    #pragma unroll
    for (int e8 = 0; e8 < N_EXP; e8++) base[e8] = wbase[w][e8];
    #pragma unroll
    for (int r = 0; r < 8; r++) {
        int i = w * 512 + r * 64 + lane;
        int e = mye[r];
        int pos = 0;
        #pragma unroll
        for (int e8 = 0; e8 < N_EXP; e8++) {
            unsigned long long m = __ballot(e == e8);
            if (e == e8) pos = base[e8] + (int)__popcll(m & lt);
            base[e8] += (int)__popcll(m);
        }
        rowpos[i] = pos;
        rowtok[pos] = i >> 1;
    }
}

template<int YBF16>
__global__ __launch_bounds__(512) void combine_kernel(
    const float* __restrict__ x1, const void* __restrict__ y,
    const int* __restrict__ topi, const float* __restrict__ gates,
    const int* __restrict__ rowpos, const float* __restrict__ b2l,
    float* __restrict__ out)
{
    const int t = blockIdx.x, d = threadIdx.x;
    int e0 = topi[2 * t], e1 = topi[2 * t + 1];
    float g0 = gates[2 * t], g1 = gates[2 * t + 1];
    int r0 = rowpos[2 * t], r1 = rowpos[2 * t + 1];
    float y0, y1;
    if (YBF16) {
        const unsigned short* yp = (const unsigned short*)y;
        y0 = bf2f(yp[(size_t)r0 * D_MODEL + d]);
        y1 = bf2f(yp[(size_t)r1 * D_MODEL + d]);
    } else {
        const float* yp = (const float*)y;
        y0 = yp[(size_t)r0 * D_MODEL + d];
        y1 = yp[(size_t)r1 * D_MODEL + d];
    }
    out[(size_t)t * D_MODEL + d] = x1[(size_t)t * D_MODEL + d]
        + g0 * (y0 + b2l[(size_t)e0 * D_MODEL + d])
        + g1 * (y1 + b2l[(size_t)e1 * D_MODEL + d]);
}

extern "C" void kernel_launch(void* const* d_in, const int* in_sizes, int n_in,
                              void* d_out, int out_size, void* d_ws, size_t ws_size,
                              hipStream_t stream)
{
    const float* x0    = (const float*)d_in[0];
    const float* ln1w  = (const float*)d_in[1];
    const float* ln1b  = (const float*)d_in[2];
    const float* wq    = (const float*)d_in[3];
    const float* wk    = (const float*)d_in[4];
    const float* wv    = (const float*)d_in[5];
    const float* wo    = (const float*)d_in[6];
    const float* bo    = (const float*)d_in[7];
    const float* ln2w  = (const float*)d_in[8];
    const float* ln2b  = (const float*)d_in[9];
    const float* gatew = (const float*)d_in[10];
    const float* w1    = (const float*)d_in[11];
    const float* b1    = (const float*)d_in[12];
    const float* w2    = (const float*)d_in[13];
    const float* b2    = (const float*)d_in[14];
    float* out = (float*)d_out;

    // ---- Time-phased workspace, total ~47.2 MiB (R2/R4-proven budget <= ~49.8) ----
    // x1 [0,8) | H [8,16): h -> attn -> h2
    //   attention phase only: Qh [0,4), Kh [4,8)  (x1 is dead there), VTh [40,44)
    // [16,40): attn phase qkvb (24 MiB)
    //   L1 MoE: yb_f32 [16,34), hmid_f32 [34,43)
    //   L2 MoE: yb_bf16 [16,25), hmid_bf16 [25,29.5), h2b [30,34)
    // W [43,47): proj wT_hi@43 (1.5M), wT_lo@45 (1.5M)
    // ints @47
    // x2 (inter-layer residual) := d_out  (safe: layer-1 combine never reads xin)
    char* ws = (char*)d_ws;
    const size_t MiB = 1 << 20;
    float* x1   = (float*)(ws + 0);
    float* h    = (float*)(ws + 8 * MiB);
    float* attn = (float*)(ws + 8 * MiB);
    float* h2   = (float*)(ws + 8 * MiB);
    float* qkvb = (float*)(ws + 16 * MiB);
    unsigned short* Qh  = (unsigned short*)(ws + 0);
    unsigned short* Kh  = (unsigned short*)(ws + 4 * MiB);
    unsigned short* VTh = (unsigned short*)(ws + 40 * MiB);
    float* yb_f32   = (float*)(ws + 16 * MiB);
    float* hmid_f32 = (float*)(ws + 34 * MiB);
    unsigned short* yb_bf16   = (unsigned short*)(ws + 16 * MiB);
    unsigned short* hmid_bf16 = (unsigned short*)(ws + 25 * MiB);
    unsigned short* h2b       = (unsigned short*)(ws + 30 * MiB);
    unsigned short* wT_hi     = (unsigned short*)(ws + 43 * MiB);
    unsigned short* wT_lo     = (unsigned short*)(ws + 45 * MiB);
    unsigned short* w1Tc_bf   = (unsigned short*)(ws + 43 * MiB);
    unsigned short* w2Tc_bf   = (unsigned short*)(ws + 45 * MiB);
    size_t oI = 47 * MiB;
    int*   topi   = (int*)(ws + oI);
    float* gates  = (float*)(ws + oI + 2 * T_TOK * 4);
    int*   rowpos = (int*)(ws + oI + 4 * T_TOK * 4);
    int*   rowtok = (int*)(ws + oI + 6 * T_TOK * 4);
    int*   meta   = (int*)(ws + oI + 6 * T_TOK * 4 + CAP * 4);
    int* offs   = meta + 16;
    float* x2 = out;   // inter-layer residual lives in d_out

    const dim3 t512(16, 16, 1);
    const dim3 tcW1(CHUNK / 32, 16, 8);   // w1 chunk [K=512, N=256]
    const dim3 tcW2(16, CHUNK / 32, 8);   // w2 chunk [K=256, N=512]
    const dim3 gQKV(QKV_LD / 128, T_TOK / 128);
    const dim3 gO(4, T_TOK / 128);
    const dim3 gUp(CHUNK / 128, CAP / 128);
    const dim3 gDn(4, CAP / 128);
    const dim3 gAttn(S_SEQ / 64, 8, 4);

    for (int l = 0; l < 2; l++) {
        const float* xin = (l == 0) ? x0 : x2;
        float* xout = (l == 1) ? out : x2;
        const float* wq_l = wq + (size_t)l * D_MODEL * D_MODEL;
        const float* wk_l = wk + (size_t)l * D_MODEL * D_MODEL;
        const float* wv_l = wv + (size_t)l * D_MODEL * D_MODEL;
        const float* wo_l = wo + (size_t)l * D_MODEL * D_MODEL;
        const float* w1_l = w1 + (size_t)l * N_EXP * D_MODEL * DH_FF;
        const float* w2_l = w2 + (size_t)l * N_EXP * DH_FF * D_MODEL;
        const float* b1_l = b1 + (size_t)l * N_EXP * DH_FF;

        ln_kernel<<<T_TOK, 256, 0, stream>>>(xin, ln1w + (size_t)l * D_MODEL,
                                             ln1b + (size_t)l * D_MODEL, h, nullptr);
        // fused QKV: wqkvT = [q|k|v] transposed+split, one MODE0 gemm N=1536
        tconv_split<<<t512, 256, 0, stream>>>(wq_l, D_MODEL, 0, wT_hi, wT_lo, D_MODEL, 0);
        tconv_split<<<t512, 256, 0, stream>>>(wk_l, D_MODEL, 0,
                                              wT_hi + 512 * 512, wT_lo + 512 * 512,
                                              D_MODEL, 0);
        tconv_split<<<t512, 256, 0, stream>>>(wv_l, D_MODEL, 0,
                                              wT_hi + 1024 * 512, wT_lo + 1024 * 512,
                                              D_MODEL, 0);
        gemm_f16x3<0><<<gQKV, 256, 0, stream>>>(h, D_MODEL, D_MODEL, wT_hi, wT_lo,
                                                D_MODEL, 0, qkvb, QKV_LD,
                                                nullptr, 0, nullptr, nullptr, nullptr, 0);
        qkv_prep<<<gAttn, 256, 0, stream>>>(qkvb, Qh, Kh, VTh);
        flash_attn_mfma<<<gAttn, 256, 0, stream>>>(Qh, Kh, VTh, attn);
        tconv_split<<<t512, 256, 0, stream>>>(wo_l, D_MODEL, 0, wT_hi, wT_lo, D_MODEL, 0);
        gemm_f16x3<1><<<gO, 256, 0, stream>>>(attn, D_MODEL, D_MODEL, wT_hi, wT_lo,
                                              D_MODEL, 0, x1, D_MODEL,
                                              bo + (size_t)l * D_MODEL, 0, xin,
                                              nullptr, nullptr, 0);
        ln_kernel<<<T_TOK, 256, 0, stream>>>(x1, ln2w + (size_t)l * D_MODEL,
                                             ln2b + (size_t)l * D_MODEL, h2,
                                             (l == 1) ? h2b : nullptr);

        hipMemsetAsync(rowtok, 0xFF, CAP * 4, stream);
        gate_kernel<<<T_TOK / 4, 256, 0, stream>>>(h2, gatew + (size_t)l * D_MODEL * N_EXP,
                                                   topi, gates);
        route_kernel<<<1, 1024, 0, stream>>>(topi, offs, rowpos, rowtok);

        if (l == 0) {
            // fp16x3 MoE: fp32-grade -> keeps L2 routing faithful
            for (int c = 0; c < DH_FF / CHUNK; c++) {
                const float* w1c = w1_l + (size_t)c * CHUNK;
                const float* b1c = b1_l + (size_t)c * CHUNK;
                const float* w2c = w2_l + (size_t)c * CHUNK * D_MODEL;
                tconv_split<<<tcW1, 256, 0, stream>>>(w1c, DH_FF, (size_t)D_MODEL * DH_FF,
                                                      wT_hi, wT_lo, D_MODEL,
                                                      (size_t)CHUNK * D_MODEL);
                gemm_f16x3<2><<<gUp, 256, 0, stream>>>(h2, D_MODEL, D_MODEL,
                                                       wT_hi, wT_lo, D_MODEL,
                                                       (size_t)CHUNK * D_MODEL,
                                                       hmid_f32, CHUNK, b1c, DH_FF,
                                                       nullptr, offs, rowtok, 0);
                tconv_split<<<tcW2, 256, 0, stream>>>(w2c, D_MODEL, (size_t)DH_FF * D_MODEL,
                                                      wT_hi, wT_lo, CHUNK,
                                                      (size_t)D_MODEL * CHUNK);
                gemm_f16x3<3><<<gDn, 256, 0, stream>>>(hmid_f32, CHUNK, CHUNK,
                                                       wT_hi, wT_lo, CHUNK,
                                                       (size_t)D_MODEL * CHUNK,
                                                       yb_f32, D_MODEL, nullptr, 0,
                                                       nullptr, offs, nullptr,
                                                       (c > 0) ? 1 : 0);
            }
            combine_kernel<0><<<T_TOK, 512, 0, stream>>>(
                x1, yb_f32, topi, gates, rowpos,
                b2 + (size_t)l * N_EXP * D_MODEL, xout);
        } else {
            // bf16 MoE (validated): post-final-gate, error only reaches output
            for (int c = 0; c < DH_FF / CHUNK; c++) {
                const float* w1c = w1_l + (size_t)c * CHUNK;
                const float* b1c = b1_l + (size_t)c * CHUNK;
                const float* w2c = w2_l + (size_t)c * CHUNK * D_MODEL;
                tconv<<<tcW1, 256, 0, stream>>>(w1c, DH_FF, (size_t)D_MODEL * DH_FF,
                                                w1Tc_bf, D_MODEL, (size_t)CHUNK * D_MODEL);
                gemm_bt<2><<<gUp, 256, 0, stream>>>(h2b, D_MODEL, D_MODEL,
                                                    w1Tc_bf, (size_t)CHUNK * D_MODEL,
                                                    hmid_bf16, CHUNK, b1c, DH_FF,
                                                    offs, rowtok, 0);
                tconv<<<tcW2, 256, 0, stream>>>(w2c, D_MODEL, (size_t)DH_FF * D_MODEL,
                                                w2Tc_bf, CHUNK, (size_t)D_MODEL * CHUNK);
                gemm_bt<3><<<gDn, 256, 0, stream>>>(hmid_bf16, CHUNK, CHUNK,
                                                    w2Tc_bf, (size_t)D_MODEL * CHUNK,
                                                    yb_bf16, D_MODEL, nullptr, 0,
                                                    offs, nullptr, (c > 0) ? 1 : 0);
            }
            combine_kernel<1><<<T_TOK, 512, 0, stream>>>(
                x1, yb_bf16, topi, gates, rowpos,
                b2 + (size_t)l * N_EXP * D_MODEL, xout);
        }
    }
}

// Round 3
// 1241.312 us; speedup vs baseline: 1.6986x; 1.3911x over previous
//
#include <hip/hip_runtime.h>
#include <cmath>

#define D_MODEL 512
#define T_TOK   4096
#define S_SEQ   1024
#define DH_FF   2048
#define N_EXP   8
#define CAP     9216    // 8192 assignments + 8*127 pad, 128-aligned
#define CHUNK   256     // MoE hidden-dim chunk
#define QKV_LD  1536

typedef __attribute__((ext_vector_type(8))) short bf16x8_t;
typedef __attribute__((ext_vector_type(4))) float f32x4_t;
typedef _Float16 f16x8 __attribute__((ext_vector_type(8)));

__device__ __forceinline__ float gelu_exact(float x) {
    return 0.5f * x * (1.0f + erff(x * 0.70710678118654752440f));
}
__device__ __forceinline__ unsigned short f2bf(float f) {
    union { float f; unsigned int u; } v; v.f = f;
    unsigned int r = v.u + 0x7fff + ((v.u >> 16) & 1);   // RNE
    return (unsigned short)(r >> 16);
}
__device__ __forceinline__ float bf2f(unsigned short u) {
    union { unsigned int i; float f; } v; v.i = ((unsigned int)u) << 16; return v.f;
}
__device__ __forceinline__ unsigned short f2h(float f) {
    _Float16 h = (_Float16)f;
    return __builtin_bit_cast(unsigned short, h);
}
// fp32 -> fp16 hi + fp16 lo (Ootomo split): v ~= hi + lo, rel err ~2^-22
__device__ __forceinline__ void split1(float v, unsigned short& h, unsigned short& l) {
    _Float16 hf = (_Float16)v;
    _Float16 lf = (_Float16)(v - (float)hf);
    h = __builtin_bit_cast(unsigned short, hf);
    l = __builtin_bit_cast(unsigned short, lf);
}

// ---------------- LayerNorm: fp32 in -> fp32 out (+ optional bf16 copy) ----------------
__global__ __launch_bounds__(256) void ln_kernel(
    const float* __restrict__ x, const float* __restrict__ w,
    const float* __restrict__ b, float* __restrict__ out,
    unsigned short* __restrict__ outb)
{
    const int t = blockIdx.x, tid = threadIdx.x;
    const float* xr = x + (size_t)t * D_MODEL;
    float v0 = xr[tid], v1 = xr[tid + 256];
    __shared__ float ss[256], sq[256];
    ss[tid] = v0 + v1;
    sq[tid] = v0 * v0 + v1 * v1;
    __syncthreads();
    for (int st = 128; st > 0; st >>= 1) {
        if (tid < st) { ss[tid] += ss[tid + st]; sq[tid] += sq[tid + st]; }
        __syncthreads();
    }
    float mu  = ss[0] * (1.0f / 512.0f);
    float var = sq[0] * (1.0f / 512.0f) - mu * mu;
    float rs  = rsqrtf(var + 1e-6f);
    float o0 = (v0 - mu) * rs * w[tid]       + b[tid];
    float o1 = (v1 - mu) * rs * w[tid + 256] + b[tid + 256];
    float* outr = out + (size_t)t * D_MODEL;
    outr[tid] = o0; outr[tid + 256] = o1;
    if (outb) {
        unsigned short* ob = outb + (size_t)t * D_MODEL;
        ob[tid] = f2bf(o0); ob[tid + 256] = f2bf(o1);
    }
}

// ================= 64x64-tile fp16x3 MFMA GEMM, fp32 weights read directly =================
// A fp32 row-major (split on the fly). B = fp32 weight [K][N] row-major, transposed+split
// in-kernel via LDS.  4 waves; wave w owns 32x32 (2x2 MFMA tiles).
// MODE 0: C = acc                      (q/k/v proj)
// MODE 1: C = acc + bias + resid       (o proj)
// MODE 2: C = gelu(acc+bias_e), A gathered via rowtok (MoE up)
// MODE 3: C (+)= acc                   (MoE down, per-expert B)
template<int MODE>
__global__ __launch_bounds__(256) void gemm64(
    const float* __restrict__ A, int lda, int KLEN,
    const float* __restrict__ Bw, int ldb, size_t BeStride,
    float* __restrict__ C, int ldc,
    const float* __restrict__ bias, int biasStride,
    const float* __restrict__ resid,
    const int* __restrict__ offs, const int* __restrict__ rowtok, int beta)
{
    __shared__ float Ts[32][68];                     // B staging (fp32, k-major)
    __shared__ unsigned short As_hi[64][40], As_lo[64][40];
    __shared__ unsigned short Bs_hi[64][40], Bs_lo[64][40];
    __shared__ int rt[64];
    const int tid = threadIdx.x;
    const int row0 = blockIdx.y * 64, col0 = blockIdx.x * 64;
    int e = 0;
    if (MODE >= 2) {
        #pragma unroll
        for (int i = 1; i < N_EXP; i++) if (offs[i] <= row0) e = i;
    }
    if (MODE == 2) {
        if (tid < 64) rt[tid] = rowtok[row0 + tid];
        __syncthreads();
    }
    const float* Be = Bw + (size_t)e * BeStride;
    const int lane = tid & 63, w = tid >> 6;
    const int wrow = (w >> 1) * 32, wcol = (w & 1) * 32;
    const int m_ = lane & 15, q_ = lane >> 4;
    f32x4_t acc[2][2];
    #pragma unroll
    for (int i = 0; i < 2; i++)
        #pragma unroll
        for (int j = 0; j < 2; j++) acc[i][j] = (f32x4_t){0.f, 0.f, 0.f, 0.f};

    const int ar = tid >> 2, ac0 = (tid & 3) * 8;    // A stage: 8 k-floats/thread
    const int bk = tid >> 3, bn0 = (tid & 7) * 8;    // B->Ts: 8 n-floats/thread
    const int tn = tid & 63, tk4 = (tid >> 6) * 4;   // Ts->Bs: 4 k/thread x2

    for (int k0 = 0; k0 < KLEN; k0 += 32) {
        {   // ---- A stage (fp32 -> hi/lo) ----
            const float* Arow;
            bool zero = false;
            if (MODE == 2) {
                int t = rt[ar];
                zero = (t < 0);
                Arow = A + (size_t)(zero ? 0 : t) * lda;
            } else {
                Arow = A + (size_t)(row0 + ar) * lda;
            }
            #pragma unroll
            for (int q = 0; q < 2; q++) {
                float4 f = zero ? make_float4(0.f, 0.f, 0.f, 0.f)
                                : *(const float4*)&Arow[k0 + ac0 + 4 * q];
                ushort4 h4, l4;
                split1(f.x, h4.x, l4.x); split1(f.y, h4.y, l4.y);
                split1(f.z, h4.z, l4.z); split1(f.w, h4.w, l4.w);
                *(ushort4*)&As_hi[ar][ac0 + 4 * q] = h4;
                *(ushort4*)&As_lo[ar][ac0 + 4 * q] = l4;
            }
        }
        {   // ---- B stage: fp32 [k][n] -> Ts ----
            const float* br = &Be[(size_t)(k0 + bk) * ldb + col0 + bn0];
            float4 f0 = *(const float4*)&br[0];
            float4 f1 = *(const float4*)&br[4];
            *(float4*)&Ts[bk][bn0]     = f0;
            *(float4*)&Ts[bk][bn0 + 4] = f1;
        }
        __syncthreads();
        // ---- transpose + split: Ts -> Bs[n][k] ----
        #pragma unroll
        for (int rep = 0; rep < 2; rep++) {
            int kk = tk4 + rep * 16;
            ushort4 h4, l4;
            split1(Ts[kk + 0][tn], h4.x, l4.x);
            split1(Ts[kk + 1][tn], h4.y, l4.y);
            split1(Ts[kk + 2][tn], h4.z, l4.z);
            split1(Ts[kk + 3][tn], h4.w, l4.w);
            *(ushort4*)&Bs_hi[tn][kk] = h4;
            *(ushort4*)&Bs_lo[tn][kk] = l4;
        }
        __syncthreads();
        // ---- fragments + 12 MFMA ----
        f16x8 ah[2], al[2], bh[2], bl[2];
        #pragma unroll
        for (int i = 0; i < 2; i++) {
            int r = wrow + 16 * i + m_;
            ah[i] = *(const f16x8*)&As_hi[r][q_ * 8];
            al[i] = *(const f16x8*)&As_lo[r][q_ * 8];
        }
        #pragma unroll
        for (int j = 0; j < 2; j++) {
            int r = wcol + 16 * j + m_;
            bh[j] = *(const f16x8*)&Bs_hi[r][q_ * 8];
            bl[j] = *(const f16x8*)&Bs_lo[r][q_ * 8];
        }
        #pragma unroll
        for (int i = 0; i < 2; i++)
            #pragma unroll
            for (int j = 0; j < 2; j++) {
                acc[i][j] = __builtin_amdgcn_mfma_f32_16x16x32_f16(ah[i], bl[j], acc[i][j], 0, 0, 0);
                acc[i][j] = __builtin_amdgcn_mfma_f32_16x16x32_f16(al[i], bh[j], acc[i][j], 0, 0, 0);
                acc[i][j] = __builtin_amdgcn_mfma_f32_16x16x32_f16(ah[i], bh[j], acc[i][j], 0, 0, 0);
            }
        __syncthreads();
    }
    // C/D layout: col = lane&15, row = (lane>>4)*4 + reg  [validated r4]
    #pragma unroll
    for (int i = 0; i < 2; i++) {
        #pragma unroll
        for (int j = 0; j < 2; j++) {
            #pragma unroll
            for (int r = 0; r < 4; r++) {
                int gr = row0 + wrow + 16 * i + q_ * 4 + r;
                int gc = col0 + wcol + 16 * j + m_;
                float v = acc[i][j][r];
                size_t idx = (size_t)gr * ldc + gc;
                if (MODE == 0) {
                    C[idx] = v;
                } else if (MODE == 1) {
                    C[idx] = v + bias[gc] + resid[idx];
                } else if (MODE == 2) {
                    C[idx] = gelu_exact(v + bias[(size_t)e * biasStride + gc]);
                } else {
                    if (beta) v += C[idx];
                    C[idx] = v;
                }
            }
        }
    }
}

// ================= 64x64-tile bf16 MFMA GEMM (L2 MoE), fp32 weights read directly =========
// MODE 2: C bf16 = gelu(acc+bias_e), A bf16 gathered via rowtok (MoE up)
// MODE 3: C bf16 (+)= acc            (MoE down)
template<int MODE>
__global__ __launch_bounds__(256) void gemm64_bt(
    const unsigned short* __restrict__ A, int lda, int KLEN,
    const float* __restrict__ Bw, int ldb, size_t BeStride,
    unsigned short* __restrict__ C, int ldc,
    const float* __restrict__ biasBase, int biasStride,
    const int* __restrict__ offs, const int* __restrict__ rowtok, int beta)
{
    __shared__ float Ts[32][68];
    __shared__ unsigned short As[64][40];
    __shared__ unsigned short Bs[64][40];
    __shared__ int rt[64];
    const int tid = threadIdx.x;
    const int row0 = blockIdx.y * 64, col0 = blockIdx.x * 64;
    int e = 0;
    #pragma unroll
    for (int i = 1; i < N_EXP; i++) if (offs[i] <= row0) e = i;
    if (MODE == 2) {
        if (tid < 64) rt[tid] = rowtok[row0 + tid];
        __syncthreads();
    }
    const float* Be = Bw + (size_t)e * BeStride;
    const int lane = tid & 63, w = tid >> 6;
    const int wrow = (w >> 1) * 32, wcol = (w & 1) * 32;
    const int m_ = lane & 15, q_ = lane >> 4;
    f32x4_t acc[2][2];
    #pragma unroll
    for (int i = 0; i < 2; i++)
        #pragma unroll
        for (int j = 0; j < 2; j++) acc[i][j] = (f32x4_t){0.f, 0.f, 0.f, 0.f};

    const int ar = tid >> 2, ac0 = (tid & 3) * 8;
    const int bk = tid >> 3, bn0 = (tid & 7) * 8;
    const int tn = tid & 63, tk4 = (tid >> 6) * 4;

    for (int k0 = 0; k0 < KLEN; k0 += 32) {
        {   // A stage (bf16 rows, possibly gathered)
            uint4 val;
            if (MODE == 2) {
                int t = rt[ar];
                val = (t >= 0) ? *(const uint4*)&A[(size_t)t * lda + k0 + ac0]
                               : make_uint4(0u, 0u, 0u, 0u);
            } else {
                val = *(const uint4*)&A[(size_t)(row0 + ar) * lda + k0 + ac0];
            }
            *(uint4*)&As[ar][ac0] = val;
        }
        {   // B stage fp32 -> Ts
            const float* br = &Be[(size_t)(k0 + bk) * ldb + col0 + bn0];
            float4 f0 = *(const float4*)&br[0];
            float4 f1 = *(const float4*)&br[4];
            *(float4*)&Ts[bk][bn0]     = f0;
            *(float4*)&Ts[bk][bn0 + 4] = f1;
        }
        __syncthreads();
        #pragma unroll
        for (int rep = 0; rep < 2; rep++) {
            int kk = tk4 + rep * 16;
            ushort4 o4;
            o4.x = f2bf(Ts[kk + 0][tn]); o4.y = f2bf(Ts[kk + 1][tn]);
            o4.z = f2bf(Ts[kk + 2][tn]); o4.w = f2bf(Ts[kk + 3][tn]);
            *(ushort4*)&Bs[tn][kk] = o4;
        }
        __syncthreads();
        bf16x8_t af[2], bfr[2];
        #pragma unroll
        for (int i = 0; i < 2; i++)
            af[i] = *(const bf16x8_t*)&As[wrow + 16 * i + m_][q_ * 8];
        #pragma unroll
        for (int j = 0; j < 2; j++)
            bfr[j] = *(const bf16x8_t*)&Bs[wcol + 16 * j + m_][q_ * 8];
        #pragma unroll
        for (int i = 0; i < 2; i++)
            #pragma unroll
            for (int j = 0; j < 2; j++)
                acc[i][j] = __builtin_amdgcn_mfma_f32_16x16x32_bf16(
                    af[i], bfr[j], acc[i][j], 0, 0, 0);
        __syncthreads();
    }
    #pragma unroll
    for (int i = 0; i < 2; i++) {
        #pragma unroll
        for (int j = 0; j < 2; j++) {
            #pragma unroll
            for (int r = 0; r < 4; r++) {
                int gr = row0 + wrow + 16 * i + q_ * 4 + r;
                int gc = col0 + wcol + 16 * j + m_;
                float v = acc[i][j][r];
                size_t idx = (size_t)gr * ldc + gc;
                if (MODE == 2) {
                    C[idx] = f2bf(gelu_exact(v + biasBase[(size_t)e * biasStride + gc]));
                } else {
                    if (beta) v += bf2f(C[idx]);
                    C[idx] = f2bf(v);
                }
            }
        }
    }
}

// ---------------- QKV prep: fp32 qkvb slab -> fp16 head-major Q (x0.125), K, V^T ----------------
// Qh/Kh: [B*H, S, 64] fp16 row-major; VTh: [B*H, 64, S] fp16 (d-major, s-contiguous).
__global__ __launch_bounds__(256) void qkv_prep(
    const float* __restrict__ qkvb, unsigned short* __restrict__ Qh,
    unsigned short* __restrict__ Kh, unsigned short* __restrict__ VTh)
{
    __shared__ float Ts[64][65];
    const int tid = threadIdx.x;
    const int t0 = blockIdx.x * 64, hh = blockIdx.y, b = blockIdx.z;
    const int bh = b * 8 + hh;
    const float* src = qkvb + ((size_t)(b * S_SEQ + t0)) * QKV_LD + hh * 64;
    #pragma unroll
    for (int i = 0; i < 4; i++) {
        int flat = tid + i * 256;
        int r = flat >> 4, c4 = (flat & 15) * 4;
        float4 qv = *(const float4*)&src[(size_t)r * QKV_LD + c4];
        float4 kv = *(const float4*)&src[(size_t)r * QKV_LD + 512 + c4];
        float4 vv = *(const float4*)&src[(size_t)r * QKV_LD + 1024 + c4];
        ushort4 qo, ko;
        qo.x = f2h(qv.x * 0.125f); qo.y = f2h(qv.y * 0.125f);
        qo.z = f2h(qv.z * 0.125f); qo.w = f2h(qv.w * 0.125f);
        ko.x = f2h(kv.x); ko.y = f2h(kv.y); ko.z = f2h(kv.z); ko.w = f2h(kv.w);
        size_t o = ((size_t)bh * S_SEQ + t0 + r) * 64 + c4;
        *(ushort4*)&Qh[o] = qo;
        *(ushort4*)&Kh[o] = ko;
        Ts[r][c4] = vv.x; Ts[r][c4 + 1] = vv.y; Ts[r][c4 + 2] = vv.z; Ts[r][c4 + 3] = vv.w;
    }
    __syncthreads();
    #pragma unroll
    for (int i = 0; i < 4; i++) {
        int flat = tid + i * 256;
        int d = flat >> 4, s4 = (flat & 15) * 4;
        ushort4 vo;
        vo.x = f2h(Ts[s4][d]);     vo.y = f2h(Ts[s4 + 1][d]);
        vo.z = f2h(Ts[s4 + 2][d]); vo.w = f2h(Ts[s4 + 3][d]);
        *(ushort4*)&VTh[((size_t)bh * 64 + d) * S_SEQ + t0 + s4] = vo;
    }
}

// ---------------- Flash attention, fp16 MFMA (fp32 softmax/accum) ----------------
__global__ __launch_bounds__(256) void flash_attn_mfma(
    const unsigned short* __restrict__ Qh, const unsigned short* __restrict__ Kh,
    const unsigned short* __restrict__ VTh, float* __restrict__ out)
{
    __shared__ unsigned short Ks[64 * 72];   // K rows kv, d-contig, +8 pad
    __shared__ unsigned short Vt[64 * 72];   // V^T rows d, kv-contig, +8 pad
    __shared__ unsigned short Ps[64 * 72];   // P rows q, kv-contig, +8 pad
    const int tid = threadIdx.x;
    const int lane = tid & 63, w = tid >> 6;
    const int m_ = lane & 15, q_ = lane >> 4;
    const int hh = blockIdx.y, b = blockIdx.z;
    const int bh = b * 8 + hh;
    const int q0 = blockIdx.x * 64;
    const size_t qbase = ((size_t)bh * S_SEQ + q0) * 64;
    const size_t kbase = (size_t)bh * S_SEQ * 64;
    const size_t vbase = (size_t)bh * 64 * S_SEQ;

    f16x8 qa[2];
    #pragma unroll
    for (int c = 0; c < 2; c++)
        qa[c] = *(const f16x8*)&Qh[qbase + (size_t)(w * 16 + m_) * 64 + c * 32 + q_ * 8];

    float m_run[4], l_run[4];
    f32x4_t acc[4];
    #pragma unroll
    for (int r = 0; r < 4; r++) { m_run[r] = -INFINITY; l_run[r] = 0.0f; }
    #pragma unroll
    for (int oj = 0; oj < 4; oj++) acc[oj] = (f32x4_t){0.f, 0.f, 0.f, 0.f};

    for (int kv0 = 0; kv0 < S_SEQ; kv0 += 64) {
        __syncthreads();   // prior PV reads of Ks/Vt done before overwrite
        #pragma unroll
        for (int i = 0; i < 2; i++) {
            int g = tid + i * 256;
            int r = g >> 3, c8 = (g & 7) * 8;
            *(uint4*)&Ks[r * 72 + c8] =
                *(const uint4*)&Kh[kbase + (size_t)(kv0 + r) * 64 + c8];
            *(uint4*)&Vt[r * 72 + c8] =
                *(const uint4*)&VTh[vbase + (size_t)r * S_SEQ + kv0 + c8];
        }
        __syncthreads();
        f32x4_t s[4];
        #pragma unroll
        for (int j = 0; j < 4; j++) s[j] = (f32x4_t){0.f, 0.f, 0.f, 0.f};
        #pragma unroll
        for (int c = 0; c < 2; c++)
            #pragma unroll
            for (int j = 0; j < 4; j++) {
                f16x8 kb = *(const f16x8*)&Ks[(j * 16 + m_) * 72 + c * 32 + q_ * 8];
                s[j] = __builtin_amdgcn_mfma_f32_16x16x32_f16(qa[c], kb, s[j], 0, 0, 0);
            }
        float alpha[4];
        #pragma unroll
        for (int r = 0; r < 4; r++) {
            float rm = fmaxf(fmaxf(s[0][r], s[1][r]), fmaxf(s[2][r], s[3][r]));
            #pragma unroll
            for (int mk = 1; mk < 16; mk <<= 1)
                rm = fmaxf(rm, __shfl_xor(rm, mk));
            float mn = fmaxf(m_run[r], rm);
            alpha[r] = __expf(m_run[r] - mn);
            m_run[r] = mn;
            float ps = 0.0f;
            #pragma unroll
            for (int j = 0; j < 4; j++) {
                float p = __expf(s[j][r] - mn);
                s[j][r] = p;
                ps += p;
            }
            #pragma unroll
            for (int mk = 1; mk < 16; mk <<= 1)
                ps += __shfl_xor(ps, mk);
            l_run[r] = l_run[r] * alpha[r] + ps;
        }
        #pragma unroll
        for (int oj = 0; oj < 4; oj++)
            #pragma unroll
            for (int r = 0; r < 4; r++)
                acc[oj][r] *= alpha[r];
        #pragma unroll
        for (int j = 0; j < 4; j++)
            #pragma unroll
            for (int r = 0; r < 4; r++)
                Ps[(w * 16 + q_ * 4 + r) * 72 + j * 16 + m_] = f2h(s[j][r]);
        __syncthreads();
        #pragma unroll
        for (int c = 0; c < 2; c++) {
            f16x8 pa = *(const f16x8*)&Ps[(w * 16 + m_) * 72 + c * 32 + q_ * 8];
            #pragma unroll
            for (int oj = 0; oj < 4; oj++) {
                f16x8 vb = *(const f16x8*)&Vt[(oj * 16 + m_) * 72 + c * 32 + q_ * 8];
                acc[oj] = __builtin_amdgcn_mfma_f32_16x16x32_f16(pa, vb, acc[oj], 0, 0, 0);
            }
        }
    }
    const size_t obase = ((size_t)b * S_SEQ + q0) * D_MODEL + hh * 64;
    #pragma unroll
    for (int r = 0; r < 4; r++) {
        float inv = 1.0f / l_run[r];
        #pragma unroll
        for (int oj = 0; oj < 4; oj++)
            out[obase + (size_t)(w * 16 + q_ * 4 + r) * D_MODEL + oj * 16 + m_] =
                acc[oj][r] * inv;
    }
}

// ---------------- Gate: 4 tokens/block, pure shuffle reduce, NO atomics ----------------
__global__ __launch_bounds__(256) void gate_kernel(
    const float* __restrict__ h, const float* __restrict__ gw,
    int* __restrict__ topi, float* __restrict__ gates)
{
    const int w = threadIdx.x >> 6, lane = threadIdx.x & 63;
    const int t = blockIdx.x * 4 + w;
    const float* hr = h + (size_t)t * D_MODEL;
    float acc[N_EXP] = {};
    for (int d = lane; d < D_MODEL; d += 64) {
        float xv = hr[d];
        const float4 g0 = *(const float4*)&gw[(size_t)d * N_EXP];
        const float4 g1 = *(const float4*)&gw[(size_t)d * N_EXP + 4];
        acc[0] += xv * g0.x; acc[1] += xv * g0.y;
        acc[2] += xv * g0.z; acc[3] += xv * g0.w;
        acc[4] += xv * g1.x; acc[5] += xv * g1.y;
        acc[6] += xv * g1.z; acc[7] += xv * g1.w;
    }
    #pragma unroll
    for (int mk = 1; mk < 64; mk <<= 1) {
        #pragma unroll
        for (int e = 0; e < N_EXP; e++) acc[e] += __shfl_xor(acc[e], mk);
    }
    if (lane == 0) {
        int e0 = 0; float v0 = acc[0];
        #pragma unroll
        for (int e = 1; e < N_EXP; e++) if (acc[e] > v0) { v0 = acc[e]; e0 = e; }
        int e1 = -1; float v1 = -INFINITY;
        #pragma unroll
        for (int e = 0; e < N_EXP; e++) if (e != e0 && acc[e] > v1) { v1 = acc[e]; e1 = e; }
        float g0 = 1.0f / (1.0f + __expf(v1 - v0));
        float g1 = 1.0f - g0;
        topi[2 * t] = e0; topi[2 * t + 1] = e1;
        gates[2 * t] = g0; gates[2 * t + 1] = g1;
    }
}

// ---------------- Route: single block, ballot-based histogram + scatter, NO atomics ----------------
__global__ __launch_bounds__(1024) void route_kernel(
    const int* __restrict__ topi, int* __restrict__ offs,
    int* __restrict__ rowpos, int* __restrict__ rowtok)
{
    __shared__ int wcnt[16][N_EXP];
    __shared__ int wbase[16][N_EXP];
    __shared__ int offs_s[N_EXP + 1];
    const int tid = threadIdx.x, w = tid >> 6, lane = tid & 63;
    const unsigned long long lt = (1ULL << lane) - 1ULL;

    int mye[8];
    int cnt[N_EXP] = {};
    #pragma unroll
    for (int r = 0; r < 8; r++) {
        int i = w * 512 + r * 64 + lane;
        int e = topi[i];
        mye[r] = e;
        #pragma unroll
        for (int e8 = 0; e8 < N_EXP; e8++) {
            unsigned long long m = __ballot(e == e8);
            cnt[e8] += (int)__popcll(m);
        }
    }
    if (lane == 0) {
        #pragma unroll
        for (int e8 = 0; e8 < N_EXP; e8++) wcnt[w][e8] = cnt[e8];
    }
    __syncthreads();
    if (tid == 0) {
        int off = 0;
        for (int e8 = 0; e8 < N_EXP; e8++) {
            offs_s[e8] = off;
            int c = 0;
            for (int ww = 0; ww < 16; ww++) c += wcnt[ww][e8];
            off += (c + 127) & ~127;
        }
        offs_s[N_EXP] = off;
        for (int e8 = 0; e8 <= N_EXP; e8++) offs[e8] = offs_s[e8];
    }
    __syncthreads();
    if (tid < 128) {
        int ww = tid >> 3, e8 = tid & 7;
        int bse = offs_s[e8];
        for (int w2 = 0; w2 < ww; w2++) bse += wcnt[w2][e8];
        wbase[ww][e8] = bse;
    }
    __syncthreads();
    int base[N_EXP];
    #pragma unroll
    for (int e8 = 0; e8 < N_EXP; e8++) base[e8] = wbase[w][e8];
    #pragma unroll
    for (int r = 0; r < 8; r++) {
        int i = w * 512 + r * 64 + lane;
        int e = mye[r];
        int pos = 0;
        #pragma unroll
        for (int e8 = 0; e8 < N_EXP; e8++) {
            unsigned long long m = __ballot(e == e8);
            if (e == e8) pos = base[e8] + (int)__popcll(m & lt);
            base[e8] += (int)__popcll(m);
        }
        rowpos[i] = pos;
        rowtok[pos] = i >> 1;
    }
}

template<int YBF16>
__global__ __launch_bounds__(512) void combine_kernel(
    const float* __restrict__ x1, const void* __restrict__ y,
    const int* __restrict__ topi, const float* __restrict__ gates,
    const int* __restrict__ rowpos, const float* __restrict__ b2l,
    float* __restrict__ out)
{
    const int t = blockIdx.x, d = threadIdx.x;
    int e0 = topi[2 * t], e1 = topi[2 * t + 1];
    float g0 = gates[2 * t], g1 = gates[2 * t + 1];
    int r0 = rowpos[2 * t], r1 = rowpos[2 * t + 1];
    float y0, y1;
    if (YBF16) {
        const unsigned short* yp = (const unsigned short*)y;
        y0 = bf2f(yp[(size_t)r0 * D_MODEL + d]);
        y1 = bf2f(yp[(size_t)r1 * D_MODEL + d]);
    } else {
        const float* yp = (const float*)y;
        y0 = yp[(size_t)r0 * D_MODEL + d];
        y1 = yp[(size_t)r1 * D_MODEL + d];
    }
    out[(size_t)t * D_MODEL + d] = x1[(size_t)t * D_MODEL + d]
        + g0 * (y0 + b2l[(size_t)e0 * D_MODEL + d])
        + g1 * (y1 + b2l[(size_t)e1 * D_MODEL + d]);
}

extern "C" void kernel_launch(void* const* d_in, const int* in_sizes, int n_in,
                              void* d_out, int out_size, void* d_ws, size_t ws_size,
                              hipStream_t stream)
{
    const float* x0    = (const float*)d_in[0];
    const float* ln1w  = (const float*)d_in[1];
    const float* ln1b  = (const float*)d_in[2];
    const float* wq    = (const float*)d_in[3];
    const float* wk    = (const float*)d_in[4];
    const float* wv    = (const float*)d_in[5];
    const float* wo    = (const float*)d_in[6];
    const float* bo    = (const float*)d_in[7];
    const float* ln2w  = (const float*)d_in[8];
    const float* ln2b  = (const float*)d_in[9];
    const float* gatew = (const float*)d_in[10];
    const float* w1    = (const float*)d_in[11];
    const float* b1    = (const float*)d_in[12];
    const float* w2    = (const float*)d_in[13];
    const float* b2    = (const float*)d_in[14];
    float* out = (float*)d_out;

    // ---- Time-phased workspace (weights now read fp32-direct; wT buffers gone) ----
    // x1 [0,8) | H [8,16): h -> attn -> h2
    //   attention phase only: Qh [0,4), Kh [4,8), VTh [40,44)
    // [16,40): attn phase qkvb (24 MiB)
    //   L1 MoE: yb_f32 [16,34), hmid_f32 [34,43)
    //   L2 MoE: yb_bf16 [16,25), hmid_bf16 [25,29.5), h2b [30,34)
    // ints @47
    char* ws = (char*)d_ws;
    const size_t MiB = 1 << 20;
    float* x1   = (float*)(ws + 0);
    float* h    = (float*)(ws + 8 * MiB);
    float* attn = (float*)(ws + 8 * MiB);
    float* h2   = (float*)(ws + 8 * MiB);
    float* qkvb = (float*)(ws + 16 * MiB);
    unsigned short* Qh  = (unsigned short*)(ws + 0);
    unsigned short* Kh  = (unsigned short*)(ws + 4 * MiB);
    unsigned short* VTh = (unsigned short*)(ws + 40 * MiB);
    float* yb_f32   = (float*)(ws + 16 * MiB);
    float* hmid_f32 = (float*)(ws + 34 * MiB);
    unsigned short* yb_bf16   = (unsigned short*)(ws + 16 * MiB);
    unsigned short* hmid_bf16 = (unsigned short*)(ws + 25 * MiB);
    unsigned short* h2b       = (unsigned short*)(ws + 30 * MiB);
    size_t oI = 47 * MiB;
    int*   topi   = (int*)(ws + oI);
    float* gates  = (float*)(ws + oI + 2 * T_TOK * 4);
    int*   rowpos = (int*)(ws + oI + 4 * T_TOK * 4);
    int*   rowtok = (int*)(ws + oI + 6 * T_TOK * 4);
    int*   meta   = (int*)(ws + oI + 6 * T_TOK * 4 + CAP * 4);
    int* offs   = meta + 16;
    float* x2 = out;   // inter-layer residual lives in d_out

    const dim3 gProj(D_MODEL / 64, T_TOK / 64);          // 8 x 64 = 512 blocks
    const dim3 gUp(CHUNK / 64, CAP / 64);                // 4 x 144 = 576 blocks
    const dim3 gDn(D_MODEL / 64, CAP / 64);              // 8 x 144 = 1152 blocks
    const dim3 gAttn(S_SEQ / 64, 8, 4);

    for (int l = 0; l < 2; l++) {
        const float* xin = (l == 0) ? x0 : x2;
        float* xout = (l == 1) ? out : x2;
        const float* wq_l = wq + (size_t)l * D_MODEL * D_MODEL;
        const float* wk_l = wk + (size_t)l * D_MODEL * D_MODEL;
        const float* wv_l = wv + (size_t)l * D_MODEL * D_MODEL;
        const float* wo_l = wo + (size_t)l * D_MODEL * D_MODEL;
        const float* w1_l = w1 + (size_t)l * N_EXP * D_MODEL * DH_FF;
        const float* w2_l = w2 + (size_t)l * N_EXP * DH_FF * D_MODEL;
        const float* b1_l = b1 + (size_t)l * N_EXP * DH_FF;

        ln_kernel<<<T_TOK, 256, 0, stream>>>(xin, ln1w + (size_t)l * D_MODEL,
                                             ln1b + (size_t)l * D_MODEL, h, nullptr);
        gemm64<0><<<gProj, 256, 0, stream>>>(h, D_MODEL, D_MODEL, wq_l, D_MODEL, 0,
                                             qkvb, QKV_LD, nullptr, 0, nullptr,
                                             nullptr, nullptr, 0);
        gemm64<0><<<gProj, 256, 0, stream>>>(h, D_MODEL, D_MODEL, wk_l, D_MODEL, 0,
                                             qkvb + 512, QKV_LD, nullptr, 0, nullptr,
                                             nullptr, nullptr, 0);
        gemm64<0><<<gProj, 256, 0, stream>>>(h, D_MODEL, D_MODEL, wv_l, D_MODEL, 0,
                                             qkvb + 1024, QKV_LD, nullptr, 0, nullptr,
                                             nullptr, nullptr, 0);
        qkv_prep<<<gAttn, 256, 0, stream>>>(qkvb, Qh, Kh, VTh);
        flash_attn_mfma<<<gAttn, 256, 0, stream>>>(Qh, Kh, VTh, attn);
        gemm64<1><<<gProj, 256, 0, stream>>>(attn, D_MODEL, D_MODEL, wo_l, D_MODEL, 0,
                                             x1, D_MODEL, bo + (size_t)l * D_MODEL, 0,
                                             xin, nullptr, nullptr, 0);
        ln_kernel<<<T_TOK, 256, 0, stream>>>(x1, ln2w + (size_t)l * D_MODEL,
                                             ln2b + (size_t)l * D_MODEL, h2,
                                             (l == 1) ? h2b : nullptr);

        hipMemsetAsync(rowtok, 0xFF, CAP * 4, stream);
        gate_kernel<<<T_TOK / 4, 256, 0, stream>>>(h2, gatew + (size_t)l * D_MODEL * N_EXP,
                                                   topi, gates);
        route_kernel<<<1, 1024, 0, stream>>>(topi, offs, rowpos, rowtok);

        if (l == 0) {
            for (int c = 0; c < DH_FF / CHUNK; c++) {
                const float* w1c = w1_l + (size_t)c * CHUNK;
                const float* b1c = b1_l + (size_t)c * CHUNK;
                const float* w2c = w2_l + (size_t)c * CHUNK * D_MODEL;
                gemm64<2><<<gUp, 256, 0, stream>>>(h2, D_MODEL, D_MODEL,
                                                   w1c, DH_FF, (size_t)D_MODEL * DH_FF,
                                                   hmid_f32, CHUNK, b1c, DH_FF,
                                                   nullptr, offs, rowtok, 0);
                gemm64<3><<<gDn, 256, 0, stream>>>(hmid_f32, CHUNK, CHUNK,
                                                   w2c, D_MODEL, (size_t)DH_FF * D_MODEL,
                                                   yb_f32, D_MODEL, nullptr, 0,
                                                   nullptr, offs, nullptr,
                                                   (c > 0) ? 1 : 0);
            }
            combine_kernel<0><<<T_TOK, 512, 0, stream>>>(
                x1, yb_f32, topi, gates, rowpos,
                b2 + (size_t)l * N_EXP * D_MODEL, xout);
        } else {
            for (int c = 0; c < DH_FF / CHUNK; c++) {
                const float* w1c = w1_l + (size_t)c * CHUNK;
                const float* b1c = b1_l + (size_t)c * CHUNK;
                const float* w2c = w2_l + (size_t)c * CHUNK * D_MODEL;
                gemm64_bt<2><<<gUp, 256, 0, stream>>>(h2b, D_MODEL, D_MODEL,
                                                      w1c, DH_FF, (size_t)D_MODEL * DH_FF,
                                                      hmid_bf16, CHUNK, b1c, DH_FF,
                                                      offs, rowtok, 0);
                gemm64_bt<3><<<gDn, 256, 0, stream>>>(hmid_bf16, CHUNK, CHUNK,
                                                      w2c, D_MODEL, (size_t)DH_FF * D_MODEL,
                                                      yb_bf16, D_MODEL, nullptr, 0,
                                                      offs, nullptr, (c > 0) ? 1 : 0);
            }
            combine_kernel<1><<<T_TOK, 512, 0, stream>>>(
                x1, yb_bf16, topi, gates, rowpos,
                b2 + (size_t)l * N_EXP * D_MODEL, xout);
        }
    }
}

// Round 4
// 947.964 us; speedup vs baseline: 2.2243x; 1.3095x over previous
//
#include <hip/hip_runtime.h>
#include <cmath>

#define D_MODEL 512
#define T_TOK   4096
#define S_SEQ   1024
#define DH_FF   2048
#define N_EXP   8
#define CAP     9216    // 8192 assignments + 8*127 pad, 128-aligned
#define QKV_LD  1536

typedef __attribute__((ext_vector_type(8))) short bf16x8_t;
typedef __attribute__((ext_vector_type(4))) float f32x4_t;
typedef _Float16 f16x8 __attribute__((ext_vector_type(8)));

__device__ __forceinline__ float gelu_exact(float x) {
    return 0.5f * x * (1.0f + erff(x * 0.70710678118654752440f));
}
__device__ __forceinline__ unsigned short f2bf(float f) {
    union { float f; unsigned int u; } v; v.f = f;
    unsigned int r = v.u + 0x7fff + ((v.u >> 16) & 1);   // RNE
    return (unsigned short)(r >> 16);
}
__device__ __forceinline__ float bf2f(unsigned short u) {
    union { unsigned int i; float f; } v; v.i = ((unsigned int)u) << 16; return v.f;
}
__device__ __forceinline__ unsigned short f2h(float f) {
    _Float16 h = (_Float16)f;
    return __builtin_bit_cast(unsigned short, h);
}
// fp32 -> fp16 hi + fp16 lo (Ootomo split): v ~= hi + lo, rel err ~2^-22
__device__ __forceinline__ void split1(float v, unsigned short& h, unsigned short& l) {
    _Float16 hf = (_Float16)v;
    _Float16 lf = (_Float16)(v - (float)hf);
    h = __builtin_bit_cast(unsigned short, hf);
    l = __builtin_bit_cast(unsigned short, lf);
}

// ---------------- LayerNorm: fp32 in -> fp32 out (+ optional bf16 copy, + raw x copy) ----------------
__global__ __launch_bounds__(256) void ln_kernel(
    const float* __restrict__ x, const float* __restrict__ w,
    const float* __restrict__ b, float* __restrict__ out,
    unsigned short* __restrict__ outb, float* __restrict__ xcopy)
{
    const int t = blockIdx.x, tid = threadIdx.x;
    const float* xr = x + (size_t)t * D_MODEL;
    float v0 = xr[tid], v1 = xr[tid + 256];
    __shared__ float ss[256], sq[256];
    ss[tid] = v0 + v1;
    sq[tid] = v0 * v0 + v1 * v1;
    __syncthreads();
    for (int st = 128; st > 0; st >>= 1) {
        if (tid < st) { ss[tid] += ss[tid + st]; sq[tid] += sq[tid + st]; }
        __syncthreads();
    }
    float mu  = ss[0] * (1.0f / 512.0f);
    float var = sq[0] * (1.0f / 512.0f) - mu * mu;
    float rs  = rsqrtf(var + 1e-6f);
    float o0 = (v0 - mu) * rs * w[tid]       + b[tid];
    float o1 = (v1 - mu) * rs * w[tid + 256] + b[tid + 256];
    float* outr = out + (size_t)t * D_MODEL;
    outr[tid] = o0; outr[tid + 256] = o1;
    if (outb) {
        unsigned short* ob = outb + (size_t)t * D_MODEL;
        ob[tid] = f2bf(o0); ob[tid + 256] = f2bf(o1);
    }
    if (xcopy) {
        float* xc = xcopy + (size_t)t * D_MODEL;
        xc[tid] = v0; xc[tid + 256] = v1;
    }
}

// ================= 64x64-tile fp16x3 MFMA GEMM, fp32 weights read directly =================
// A fp32 row-major (split on the fly). B = fp32 weight [K][N] row-major, transposed+split
// in-kernel via LDS.  4 waves; wave w owns 32x32 (2x2 MFMA tiles).
// MODE 1: C = acc + bias + resid       (o proj)
// MODE 2: C = gelu(acc+bias_e), A gathered via rowtok (MoE up)
// MODE 4: C = acc, fused QKV: blockIdx.x>>3 selects {Bw, bias(=wk), resid(=wv)}
// MODE 5: MoE down direct: atomicAdd(C[tok], rowgate*(acc + beta?bias_e:0)), skip pads
//         (rowgate passed via `resid`)
template<int MODE>
__global__ __launch_bounds__(256) void gemm64(
    const float* __restrict__ A, int lda, int KLEN,
    const float* __restrict__ Bw, int ldb, size_t BeStride,
    float* __restrict__ C, int ldc,
    const float* __restrict__ bias, int biasStride,
    const float* __restrict__ resid,
    const int* __restrict__ offs, const int* __restrict__ rowtok, int beta)
{
    __shared__ float Ts[32][68];                     // B staging (fp32, k-major)
    __shared__ unsigned short As_hi[64][40], As_lo[64][40];
    __shared__ unsigned short Bs_hi[64][40], Bs_lo[64][40];
    __shared__ int rt[64];
    __shared__ float rg[64];
    const int tid = threadIdx.x;
    const int row0 = blockIdx.y * 64, col0 = blockIdx.x * 64;
    int e = 0;
    if (MODE == 2 || MODE == 5) {
        #pragma unroll
        for (int i = 1; i < N_EXP; i++) if (offs[i] <= row0) e = i;
        if (tid < 64) rt[tid] = rowtok[row0 + tid];
        if (MODE == 5 && tid >= 64 && tid < 128) rg[tid - 64] = resid[row0 + tid - 64];
        __syncthreads();
    }
    const float* Be = Bw + (size_t)e * BeStride;
    int colB = col0;
    if (MODE == 4) {
        int sel = blockIdx.x >> 3;
        Be = (sel == 0) ? Bw : (sel == 1) ? bias : resid;
        colB = (blockIdx.x & 7) * 64;
    }
    const int lane = tid & 63, w = tid >> 6;
    const int wrow = (w >> 1) * 32, wcol = (w & 1) * 32;
    const int m_ = lane & 15, q_ = lane >> 4;
    f32x4_t acc[2][2];
    #pragma unroll
    for (int i = 0; i < 2; i++)
        #pragma unroll
        for (int j = 0; j < 2; j++) acc[i][j] = (f32x4_t){0.f, 0.f, 0.f, 0.f};

    const int ar = tid >> 2, ac0 = (tid & 3) * 8;    // A stage: 8 k-floats/thread
    const int bk = tid >> 3, bn0 = (tid & 7) * 8;    // B->Ts: 8 n-floats/thread
    const int tn = tid & 63, tk4 = (tid >> 6) * 4;   // Ts->Bs: 4 k/thread x2

    for (int k0 = 0; k0 < KLEN; k0 += 32) {
        {   // ---- A stage (fp32 -> hi/lo) ----
            const float* Arow;
            bool zero = false;
            if (MODE == 2) {
                int t = rt[ar];
                zero = (t < 0);
                Arow = A + (size_t)(zero ? 0 : t) * lda;
            } else {
                Arow = A + (size_t)(row0 + ar) * lda;
            }
            #pragma unroll
            for (int q = 0; q < 2; q++) {
                float4 f = zero ? make_float4(0.f, 0.f, 0.f, 0.f)
                                : *(const float4*)&Arow[k0 + ac0 + 4 * q];
                ushort4 h4, l4;
                split1(f.x, h4.x, l4.x); split1(f.y, h4.y, l4.y);
                split1(f.z, h4.z, l4.z); split1(f.w, h4.w, l4.w);
                *(ushort4*)&As_hi[ar][ac0 + 4 * q] = h4;
                *(ushort4*)&As_lo[ar][ac0 + 4 * q] = l4;
            }
        }
        {   // ---- B stage: fp32 [k][n] -> Ts ----
            const float* br = &Be[(size_t)(k0 + bk) * ldb + colB + bn0];
            float4 f0 = *(const float4*)&br[0];
            float4 f1 = *(const float4*)&br[4];
            *(float4*)&Ts[bk][bn0]     = f0;
            *(float4*)&Ts[bk][bn0 + 4] = f1;
        }
        __syncthreads();
        // ---- transpose + split: Ts -> Bs[n][k] ----
        #pragma unroll
        for (int rep = 0; rep < 2; rep++) {
            int kk = tk4 + rep * 16;
            ushort4 h4, l4;
            split1(Ts[kk + 0][tn], h4.x, l4.x);
            split1(Ts[kk + 1][tn], h4.y, l4.y);
            split1(Ts[kk + 2][tn], h4.z, l4.z);
            split1(Ts[kk + 3][tn], h4.w, l4.w);
            *(ushort4*)&Bs_hi[tn][kk] = h4;
            *(ushort4*)&Bs_lo[tn][kk] = l4;
        }
        __syncthreads();
        // ---- fragments + 12 MFMA ----
        f16x8 ah[2], al[2], bh[2], bl[2];
        #pragma unroll
        for (int i = 0; i < 2; i++) {
            int r = wrow + 16 * i + m_;
            ah[i] = *(const f16x8*)&As_hi[r][q_ * 8];
            al[i] = *(const f16x8*)&As_lo[r][q_ * 8];
        }
        #pragma unroll
        for (int j = 0; j < 2; j++) {
            int r = wcol + 16 * j + m_;
            bh[j] = *(const f16x8*)&Bs_hi[r][q_ * 8];
            bl[j] = *(const f16x8*)&Bs_lo[r][q_ * 8];
        }
        #pragma unroll
        for (int i = 0; i < 2; i++)
            #pragma unroll
            for (int j = 0; j < 2; j++) {
                acc[i][j] = __builtin_amdgcn_mfma_f32_16x16x32_f16(ah[i], bl[j], acc[i][j], 0, 0, 0);
                acc[i][j] = __builtin_amdgcn_mfma_f32_16x16x32_f16(al[i], bh[j], acc[i][j], 0, 0, 0);
                acc[i][j] = __builtin_amdgcn_mfma_f32_16x16x32_f16(ah[i], bh[j], acc[i][j], 0, 0, 0);
            }
        __syncthreads();
    }
    // C/D layout: col = lane&15, row = (lane>>4)*4 + reg  [validated r4]
    #pragma unroll
    for (int i = 0; i < 2; i++) {
        #pragma unroll
        for (int j = 0; j < 2; j++) {
            #pragma unroll
            for (int r = 0; r < 4; r++) {
                int lr = wrow + 16 * i + q_ * 4 + r;
                int gr = row0 + lr;
                int gc = col0 + wcol + 16 * j + m_;
                float v = acc[i][j][r];
                if (MODE == 5) {
                    int t = rt[lr];
                    if (t >= 0) {
                        float add = beta ? bias[(size_t)e * biasStride + gc] : 0.0f;
                        atomicAdd(&C[(size_t)t * ldc + gc], rg[lr] * (v + add));
                    }
                } else {
                    size_t idx = (size_t)gr * ldc + gc;
                    if (MODE == 1) {
                        C[idx] = v + bias[gc] + resid[idx];
                    } else if (MODE == 2) {
                        C[idx] = gelu_exact(v + bias[(size_t)e * biasStride + gc]);
                    } else {   // MODE 4
                        C[idx] = v;
                    }
                }
            }
        }
    }
}

// ================= 64x64-tile bf16 MFMA GEMM (L2 MoE), fp32 weights read directly =========
// MODE 2: C bf16 = gelu(acc+bias_e), A bf16 gathered via rowtok (MoE up)
// MODE 5: MoE down direct: atomicAdd(Cout[tok], rowgate*(acc + beta?bias_e:0)), skip pads
template<int MODE>
__global__ __launch_bounds__(256) void gemm64_bt(
    const unsigned short* __restrict__ A, int lda, int KLEN,
    const float* __restrict__ Bw, int ldb, size_t BeStride,
    unsigned short* __restrict__ C, int ldc,
    const float* __restrict__ biasBase, int biasStride,
    const int* __restrict__ offs, const int* __restrict__ rowtok,
    const float* __restrict__ rowgate, float* __restrict__ Cout, int beta)
{
    __shared__ float Ts[32][68];
    __shared__ unsigned short As[64][40];
    __shared__ unsigned short Bs[64][40];
    __shared__ int rt[64];
    __shared__ float rg[64];
    const int tid = threadIdx.x;
    const int row0 = blockIdx.y * 64, col0 = blockIdx.x * 64;
    int e = 0;
    #pragma unroll
    for (int i = 1; i < N_EXP; i++) if (offs[i] <= row0) e = i;
    if (tid < 64) rt[tid] = rowtok[row0 + tid];
    if (MODE == 5 && tid >= 64 && tid < 128) rg[tid - 64] = rowgate[row0 + tid - 64];
    __syncthreads();
    const float* Be = Bw + (size_t)e * BeStride;
    const int lane = tid & 63, w = tid >> 6;
    const int wrow = (w >> 1) * 32, wcol = (w & 1) * 32;
    const int m_ = lane & 15, q_ = lane >> 4;
    f32x4_t acc[2][2];
    #pragma unroll
    for (int i = 0; i < 2; i++)
        #pragma unroll
        for (int j = 0; j < 2; j++) acc[i][j] = (f32x4_t){0.f, 0.f, 0.f, 0.f};

    const int ar = tid >> 2, ac0 = (tid & 3) * 8;
    const int bk = tid >> 3, bn0 = (tid & 7) * 8;
    const int tn = tid & 63, tk4 = (tid >> 6) * 4;

    for (int k0 = 0; k0 < KLEN; k0 += 32) {
        {   // A stage (bf16 rows, possibly gathered)
            uint4 val;
            if (MODE == 2) {
                int t = rt[ar];
                val = (t >= 0) ? *(const uint4*)&A[(size_t)t * lda + k0 + ac0]
                               : make_uint4(0u, 0u, 0u, 0u);
            } else {
                val = *(const uint4*)&A[(size_t)(row0 + ar) * lda + k0 + ac0];
            }
            *(uint4*)&As[ar][ac0] = val;
        }
        {   // B stage fp32 -> Ts
            const float* br = &Be[(size_t)(k0 + bk) * ldb + col0 + bn0];
            float4 f0 = *(const float4*)&br[0];
            float4 f1 = *(const float4*)&br[4];
            *(float4*)&Ts[bk][bn0]     = f0;
            *(float4*)&Ts[bk][bn0 + 4] = f1;
        }
        __syncthreads();
        #pragma unroll
        for (int rep = 0; rep < 2; rep++) {
            int kk = tk4 + rep * 16;
            ushort4 o4;
            o4.x = f2bf(Ts[kk + 0][tn]); o4.y = f2bf(Ts[kk + 1][tn]);
            o4.z = f2bf(Ts[kk + 2][tn]); o4.w = f2bf(Ts[kk + 3][tn]);
            *(ushort4*)&Bs[tn][kk] = o4;
        }
        __syncthreads();
        bf16x8_t af[2], bfr[2];
        #pragma unroll
        for (int i = 0; i < 2; i++)
            af[i] = *(const bf16x8_t*)&As[wrow + 16 * i + m_][q_ * 8];
        #pragma unroll
        for (int j = 0; j < 2; j++)
            bfr[j] = *(const bf16x8_t*)&Bs[wcol + 16 * j + m_][q_ * 8];
        #pragma unroll
        for (int i = 0; i < 2; i++)
            #pragma unroll
            for (int j = 0; j < 2; j++)
                acc[i][j] = __builtin_amdgcn_mfma_f32_16x16x32_bf16(
                    af[i], bfr[j], acc[i][j], 0, 0, 0);
        __syncthreads();
    }
    #pragma unroll
    for (int i = 0; i < 2; i++) {
        #pragma unroll
        for (int j = 0; j < 2; j++) {
            #pragma unroll
            for (int r = 0; r < 4; r++) {
                int lr = wrow + 16 * i + q_ * 4 + r;
                int gr = row0 + lr;
                int gc = col0 + wcol + 16 * j + m_;
                float v = acc[i][j][r];
                if (MODE == 5) {
                    int t = rt[lr];
                    if (t >= 0) {
                        float add = beta ? biasBase[(size_t)e * biasStride + gc] : 0.0f;
                        atomicAdd(&Cout[(size_t)t * ldc + gc], rg[lr] * (v + add));
                    }
                } else {
                    size_t idx = (size_t)gr * ldc + gc;
                    C[idx] = f2bf(gelu_exact(v + biasBase[(size_t)e * biasStride + gc]));
                }
            }
        }
    }
}

// ---------------- QKV prep: fp32 qkvb slab -> fp16 head-major Q (x0.125), K, V^T ----------------
// Qh/Kh: [B*H, S, 64] fp16 row-major; VTh: [B*H, 64, S] fp16 (d-major, s-contiguous).
__global__ __launch_bounds__(256) void qkv_prep(
    const float* __restrict__ qkvb, unsigned short* __restrict__ Qh,
    unsigned short* __restrict__ Kh, unsigned short* __restrict__ VTh)
{
    __shared__ float Ts[64][65];
    const int tid = threadIdx.x;
    const int t0 = blockIdx.x * 64, hh = blockIdx.y, b = blockIdx.z;
    const int bh = b * 8 + hh;
    const float* src = qkvb + ((size_t)(b * S_SEQ + t0)) * QKV_LD + hh * 64;
    #pragma unroll
    for (int i = 0; i < 4; i++) {
        int flat = tid + i * 256;
        int r = flat >> 4, c4 = (flat & 15) * 4;
        float4 qv = *(const float4*)&src[(size_t)r * QKV_LD + c4];
        float4 kv = *(const float4*)&src[(size_t)r * QKV_LD + 512 + c4];
        float4 vv = *(const float4*)&src[(size_t)r * QKV_LD + 1024 + c4];
        ushort4 qo, ko;
        qo.x = f2h(qv.x * 0.125f); qo.y = f2h(qv.y * 0.125f);
        qo.z = f2h(qv.z * 0.125f); qo.w = f2h(qv.w * 0.125f);
        ko.x = f2h(kv.x); ko.y = f2h(kv.y); ko.z = f2h(kv.z); ko.w = f2h(kv.w);
        size_t o = ((size_t)bh * S_SEQ + t0 + r) * 64 + c4;
        *(ushort4*)&Qh[o] = qo;
        *(ushort4*)&Kh[o] = ko;
        Ts[r][c4] = vv.x; Ts[r][c4 + 1] = vv.y; Ts[r][c4 + 2] = vv.z; Ts[r][c4 + 3] = vv.w;
    }
    __syncthreads();
    #pragma unroll
    for (int i = 0; i < 4; i++) {
        int flat = tid + i * 256;
        int d = flat >> 4, s4 = (flat & 15) * 4;
        ushort4 vo;
        vo.x = f2h(Ts[s4][d]);     vo.y = f2h(Ts[s4 + 1][d]);
        vo.z = f2h(Ts[s4 + 2][d]); vo.w = f2h(Ts[s4 + 3][d]);
        *(ushort4*)&VTh[((size_t)bh * 64 + d) * S_SEQ + t0 + s4] = vo;
    }
}

// ---------------- Flash attention, fp16 MFMA (fp32 softmax/accum) ----------------
__global__ __launch_bounds__(256) void flash_attn_mfma(
    const unsigned short* __restrict__ Qh, const unsigned short* __restrict__ Kh,
    const unsigned short* __restrict__ VTh, float* __restrict__ out)
{
    __shared__ unsigned short Ks[64 * 72];   // K rows kv, d-contig, +8 pad
    __shared__ unsigned short Vt[64 * 72];   // V^T rows d, kv-contig, +8 pad
    __shared__ unsigned short Ps[64 * 72];   // P rows q, kv-contig, +8 pad
    const int tid = threadIdx.x;
    const int lane = tid & 63, w = tid >> 6;
    const int m_ = lane & 15, q_ = lane >> 4;
    const int hh = blockIdx.y, b = blockIdx.z;
    const int bh = b * 8 + hh;
    const int q0 = blockIdx.x * 64;
    const size_t qbase = ((size_t)bh * S_SEQ + q0) * 64;
    const size_t kbase = (size_t)bh * S_SEQ * 64;
    const size_t vbase = (size_t)bh * 64 * S_SEQ;

    f16x8 qa[2];
    #pragma unroll
    for (int c = 0; c < 2; c++)
        qa[c] = *(const f16x8*)&Qh[qbase + (size_t)(w * 16 + m_) * 64 + c * 32 + q_ * 8];

    float m_run[4], l_run[4];
    f32x4_t acc[4];
    #pragma unroll
    for (int r = 0; r < 4; r++) { m_run[r] = -INFINITY; l_run[r] = 0.0f; }
    #pragma unroll
    for (int oj = 0; oj < 4; oj++) acc[oj] = (f32x4_t){0.f, 0.f, 0.f, 0.f};

    for (int kv0 = 0; kv0 < S_SEQ; kv0 += 64) {
        __syncthreads();   // prior PV reads of Ks/Vt done before overwrite
        #pragma unroll
        for (int i = 0; i < 2; i++) {
            int g = tid + i * 256;
            int r = g >> 3, c8 = (g & 7) * 8;
            *(uint4*)&Ks[r * 72 + c8] =
                *(const uint4*)&Kh[kbase + (size_t)(kv0 + r) * 64 + c8];
            *(uint4*)&Vt[r * 72 + c8] =
                *(const uint4*)&VTh[vbase + (size_t)r * S_SEQ + kv0 + c8];
        }
        __syncthreads();
        f32x4_t s[4];
        #pragma unroll
        for (int j = 0; j < 4; j++) s[j] = (f32x4_t){0.f, 0.f, 0.f, 0.f};
        #pragma unroll
        for (int c = 0; c < 2; c++)
            #pragma unroll
            for (int j = 0; j < 4; j++) {
                f16x8 kb = *(const f16x8*)&Ks[(j * 16 + m_) * 72 + c * 32 + q_ * 8];
                s[j] = __builtin_amdgcn_mfma_f32_16x16x32_f16(qa[c], kb, s[j], 0, 0, 0);
            }
        float alpha[4];
        #pragma unroll
        for (int r = 0; r < 4; r++) {
            float rm = fmaxf(fmaxf(s[0][r], s[1][r]), fmaxf(s[2][r], s[3][r]));
            #pragma unroll
            for (int mk = 1; mk < 16; mk <<= 1)
                rm = fmaxf(rm, __shfl_xor(rm, mk));
            float mn = fmaxf(m_run[r], rm);
            alpha[r] = __expf(m_run[r] - mn);
            m_run[r] = mn;
            float ps = 0.0f;
            #pragma unroll
            for (int j = 0; j < 4; j++) {
                float p = __expf(s[j][r] - mn);
                s[j][r] = p;
                ps += p;
            }
            #pragma unroll
            for (int mk = 1; mk < 16; mk <<= 1)
                ps += __shfl_xor(ps, mk);
            l_run[r] = l_run[r] * alpha[r] + ps;
        }
        #pragma unroll
        for (int oj = 0; oj < 4; oj++)
            #pragma unroll
            for (int r = 0; r < 4; r++)
                acc[oj][r] *= alpha[r];
        #pragma unroll
        for (int j = 0; j < 4; j++)
            #pragma unroll
            for (int r = 0; r < 4; r++)
                Ps[(w * 16 + q_ * 4 + r) * 72 + j * 16 + m_] = f2h(s[j][r]);
        __syncthreads();
        #pragma unroll
        for (int c = 0; c < 2; c++) {
            f16x8 pa = *(const f16x8*)&Ps[(w * 16 + m_) * 72 + c * 32 + q_ * 8];
            #pragma unroll
            for (int oj = 0; oj < 4; oj++) {
                f16x8 vb = *(const f16x8*)&Vt[(oj * 16 + m_) * 72 + c * 32 + q_ * 8];
                acc[oj] = __builtin_amdgcn_mfma_f32_16x16x32_f16(pa, vb, acc[oj], 0, 0, 0);
            }
        }
    }
    const size_t obase = ((size_t)b * S_SEQ + q0) * D_MODEL + hh * 64;
    #pragma unroll
    for (int r = 0; r < 4; r++) {
        float inv = 1.0f / l_run[r];
        #pragma unroll
        for (int oj = 0; oj < 4; oj++)
            out[obase + (size_t)(w * 16 + q_ * 4 + r) * D_MODEL + oj * 16 + m_] =
                acc[oj][r] * inv;
    }
}

// ---------------- Gate: 4 tokens/block, pure shuffle reduce, NO atomics ----------------
__global__ __launch_bounds__(256) void gate_kernel(
    const float* __restrict__ h, const float* __restrict__ gw,
    int* __restrict__ topi, float* __restrict__ gates)
{
    const int w = threadIdx.x >> 6, lane = threadIdx.x & 63;
    const int t = blockIdx.x * 4 + w;
    const float* hr = h + (size_t)t * D_MODEL;
    float acc[N_EXP] = {};
    for (int d = lane; d < D_MODEL; d += 64) {
        float xv = hr[d];
        const float4 g0 = *(const float4*)&gw[(size_t)d * N_EXP];
        const float4 g1 = *(const float4*)&gw[(size_t)d * N_EXP + 4];
        acc[0] += xv * g0.x; acc[1] += xv * g0.y;
        acc[2] += xv * g0.z; acc[3] += xv * g0.w;
        acc[4] += xv * g1.x; acc[5] += xv * g1.y;
        acc[6] += xv * g1.z; acc[7] += xv * g1.w;
    }
    #pragma unroll
    for (int mk = 1; mk < 64; mk <<= 1) {
        #pragma unroll
        for (int e = 0; e < N_EXP; e++) acc[e] += __shfl_xor(acc[e], mk);
    }
    if (lane == 0) {
        int e0 = 0; float v0 = acc[0];
        #pragma unroll
        for (int e = 1; e < N_EXP; e++) if (acc[e] > v0) { v0 = acc[e]; e0 = e; }
        int e1 = -1; float v1 = -INFINITY;
        #pragma unroll
        for (int e = 0; e < N_EXP; e++) if (e != e0 && acc[e] > v1) { v1 = acc[e]; e1 = e; }
        float g0 = 1.0f / (1.0f + __expf(v1 - v0));
        float g1 = 1.0f - g0;
        topi[2 * t] = e0; topi[2 * t + 1] = e1;
        gates[2 * t] = g0; gates[2 * t + 1] = g1;
    }
}

// ---------------- Route: single block, ballot-based histogram + scatter, NO atomics ----------------
__global__ __launch_bounds__(1024) void route_kernel(
    const int* __restrict__ topi, const float* __restrict__ gates,
    int* __restrict__ offs, int* __restrict__ rowtok, float* __restrict__ rowgate)
{
    __shared__ int wcnt[16][N_EXP];
    __shared__ int wbase[16][N_EXP];
    __shared__ int offs_s[N_EXP + 1];
    const int tid = threadIdx.x, w = tid >> 6, lane = tid & 63;
    const unsigned long long lt = (1ULL << lane) - 1ULL;

    int mye[8];
    int cnt[N_EXP] = {};
    #pragma unroll
    for (int r = 0; r < 8; r++) {
        int i = w * 512 + r * 64 + lane;
        int e = topi[i];
        mye[r] = e;
        #pragma unroll
        for (int e8 = 0; e8 < N_EXP; e8++) {
            unsigned long long m = __ballot(e == e8);
            cnt[e8] += (int)__popcll(m);
        }
    }
    if (lane == 0) {
        #pragma unroll
        for (int e8 = 0; e8 < N_EXP; e8++) wcnt[w][e8] = cnt[e8];
    }
    __syncthreads();
    if (tid == 0) {
        int off = 0;
        for (int e8 = 0; e8 < N_EXP; e8++) {
            offs_s[e8] = off;
            int c = 0;
            for (int ww = 0; ww < 16; ww++) c += wcnt[ww][e8];
            off += (c + 127) & ~127;
        }
        offs_s[N_EXP] = off;
        for (int e8 = 0; e8 <= N_EXP; e8++) offs[e8] = offs_s[e8];
    }
    __syncthreads();
    if (tid < 128) {
        int ww = tid >> 3, e8 = tid & 7;
        int bse = offs_s[e8];
        for (int w2 = 0; w2 < ww; w2++) bse += wcnt[w2][e8];
        wbase[ww][e8] = bse;
    }
    __syncthreads();
    int base[N_EXP];
    #pragma unroll
    for (int e8 = 0; e8 < N_EXP; e8++) base[e8] = wbase[w][e8];
    #pragma unroll
    for (int r = 0; r < 8; r++) {
        int i = w * 512 + r * 64 + lane;
        int e = mye[r];
        int pos = 0;
        #pragma unroll
        for (int e8 = 0; e8 < N_EXP; e8++) {
            unsigned long long m = __ballot(e == e8);
            if (e == e8) pos = base[e8] + (int)__popcll(m & lt);
            base[e8] += (int)__popcll(m);
        }
        rowtok[pos] = i >> 1;
        rowgate[pos] = gates[i];
    }
}

extern "C" void kernel_launch(void* const* d_in, const int* in_sizes, int n_in,
                              void* d_out, int out_size, void* d_ws, size_t ws_size,
                              hipStream_t stream)
{
    const float* x0    = (const float*)d_in[0];
    const float* ln1w  = (const float*)d_in[1];
    const float* ln1b  = (const float*)d_in[2];
    const float* wq    = (const float*)d_in[3];
    const float* wk    = (const float*)d_in[4];
    const float* wv    = (const float*)d_in[5];
    const float* wo    = (const float*)d_in[6];
    const float* bo    = (const float*)d_in[7];
    const float* ln2w  = (const float*)d_in[8];
    const float* ln2b  = (const float*)d_in[9];
    const float* gatew = (const float*)d_in[10];
    const float* w1    = (const float*)d_in[11];
    const float* b1    = (const float*)d_in[12];
    const float* w2    = (const float*)d_in[13];
    const float* b2    = (const float*)d_in[14];
    float* out = (float*)d_out;

    // ---- Time-phased workspace ----
    // x1 [0,8) | H [8,16): h -> attn -> h2
    //   attention phase only: Qh [0,4), Kh [4,8), VTh [40,44)
    // [16,40): attn phase qkvb (24 MiB)
    //   MoE phase: hmid_f32 (L1, 18.9 MB) / hmid_bf16 (L2, 18.9 MB) @16
    // h2b @43 (4 MB, L2 only; VTh dead by then)
    // ints @47
    // x2 (inter-layer residual) := d_out; residual seeded into xout by LN2's xcopy,
    // MoE down-GEMMs accumulate atomically on top.
    char* ws = (char*)d_ws;
    const size_t MiB = 1 << 20;
    float* x1   = (float*)(ws + 0);
    float* h    = (float*)(ws + 8 * MiB);
    float* attn = (float*)(ws + 8 * MiB);
    float* h2   = (float*)(ws + 8 * MiB);
    float* qkvb = (float*)(ws + 16 * MiB);
    unsigned short* Qh  = (unsigned short*)(ws + 0);
    unsigned short* Kh  = (unsigned short*)(ws + 4 * MiB);
    unsigned short* VTh = (unsigned short*)(ws + 40 * MiB);
    float* hmid_f32 = (float*)(ws + 16 * MiB);
    unsigned short* hmid_bf16 = (unsigned short*)(ws + 16 * MiB);
    unsigned short* h2b       = (unsigned short*)(ws + 43 * MiB);
    size_t oI = 47 * MiB;
    int*   topi    = (int*)(ws + oI);
    float* gates   = (float*)(ws + oI + 2 * T_TOK * 4);
    int*   rowtok  = (int*)(ws + oI + 4 * T_TOK * 4);
    float* rowgate = (float*)(ws + oI + 4 * T_TOK * 4 + CAP * 4);
    int*   meta    = (int*)(ws + oI + 4 * T_TOK * 4 + 2 * CAP * 4);
    int* offs = meta;
    float* x2 = out;   // inter-layer residual lives in d_out

    const dim3 gQKV(24, T_TOK / 64);           // 1536 blocks
    const dim3 gO(D_MODEL / 64, T_TOK / 64);   // 512 blocks
    const dim3 gUp1(8, CAP / 64);              // L1 up: CHUNK=512 -> 1152 blocks
    const dim3 gDn1(D_MODEL / 64, CAP / 64);   // L1 down: 1152 blocks
    const dim3 gUp2(16, CAP / 64);             // L2 up: CHUNK=1024 -> 2304 blocks
    const dim3 gDn2(D_MODEL / 64, CAP / 64);   // L2 down: 1152 blocks
    const dim3 gAttn(S_SEQ / 64, 8, 4);

    for (int l = 0; l < 2; l++) {
        const float* xin = (l == 0) ? x0 : x2;
        float* xout = (l == 1) ? out : x2;
        const float* wq_l = wq + (size_t)l * D_MODEL * D_MODEL;
        const float* wk_l = wk + (size_t)l * D_MODEL * D_MODEL;
        const float* wv_l = wv + (size_t)l * D_MODEL * D_MODEL;
        const float* wo_l = wo + (size_t)l * D_MODEL * D_MODEL;
        const float* w1_l = w1 + (size_t)l * N_EXP * D_MODEL * DH_FF;
        const float* w2_l = w2 + (size_t)l * N_EXP * DH_FF * D_MODEL;
        const float* b1_l = b1 + (size_t)l * N_EXP * DH_FF;
        const float* b2_l = b2 + (size_t)l * N_EXP * D_MODEL;

        ln_kernel<<<T_TOK, 256, 0, stream>>>(xin, ln1w + (size_t)l * D_MODEL,
                                             ln1b + (size_t)l * D_MODEL, h,
                                             nullptr, nullptr);
        // fused QKV: one dispatch, blockIdx.x>>3 selects wq/wk/wv
        gemm64<4><<<gQKV, 256, 0, stream>>>(h, D_MODEL, D_MODEL, wq_l, D_MODEL, 0,
                                            qkvb, QKV_LD, wk_l, 0, wv_l,
                                            nullptr, nullptr, 0);
        qkv_prep<<<gAttn, 256, 0, stream>>>(qkvb, Qh, Kh, VTh);
        flash_attn_mfma<<<gAttn, 256, 0, stream>>>(Qh, Kh, VTh, attn);
        gemm64<1><<<gO, 256, 0, stream>>>(attn, D_MODEL, D_MODEL, wo_l, D_MODEL, 0,
                                          x1, D_MODEL, bo + (size_t)l * D_MODEL, 0,
                                          xin, nullptr, nullptr, 0);
        // LN2: h2 (+ bf16 copy for L2 MoE) + seed xout with residual x1
        ln_kernel<<<T_TOK, 256, 0, stream>>>(x1, ln2w + (size_t)l * D_MODEL,
                                             ln2b + (size_t)l * D_MODEL, h2,
                                             (l == 1) ? h2b : nullptr, xout);

        hipMemsetAsync(rowtok, 0xFF, CAP * 4, stream);
        gate_kernel<<<T_TOK / 4, 256, 0, stream>>>(h2, gatew + (size_t)l * D_MODEL * N_EXP,
                                                   topi, gates);
        route_kernel<<<1, 1024, 0, stream>>>(topi, gates, offs, rowtok, rowgate);

        if (l == 0) {
            // fp16x3 MoE, CHUNK=512: 4 up + 4 down; down accumulates into xout atomically
            for (int c = 0; c < 4; c++) {
                gemm64<2><<<gUp1, 256, 0, stream>>>(h2, D_MODEL, D_MODEL,
                                                    w1_l + (size_t)c * 512, DH_FF,
                                                    (size_t)D_MODEL * DH_FF,
                                                    hmid_f32, 512,
                                                    b1_l + (size_t)c * 512, DH_FF,
                                                    nullptr, offs, rowtok, 0);
                gemm64<5><<<gDn1, 256, 0, stream>>>(hmid_f32, 512, 512,
                                                    w2_l + (size_t)c * 512 * D_MODEL,
                                                    D_MODEL, (size_t)DH_FF * D_MODEL,
                                                    xout, D_MODEL, b2_l, D_MODEL,
                                                    rowgate, offs, rowtok,
                                                    (c == 0) ? 1 : 0);
            }
        } else {
            // bf16 MoE, CHUNK=1024: 2 up + 2 down; fp32 atomic accumulate into xout
            for (int c = 0; c < 2; c++) {
                gemm64_bt<2><<<gUp2, 256, 0, stream>>>(h2b, D_MODEL, D_MODEL,
                                                       w1_l + (size_t)c * 1024, DH_FF,
                                                       (size_t)D_MODEL * DH_FF,
                                                       hmid_bf16, 1024,
                                                       b1_l + (size_t)c * 1024, DH_FF,
                                                       offs, rowtok, nullptr, nullptr, 0);
                gemm64_bt<5><<<gDn2, 256, 0, stream>>>(hmid_bf16, 1024, 1024,
                                                       w2_l + (size_t)c * 1024 * D_MODEL,
                                                       D_MODEL, (size_t)DH_FF * D_MODEL,
                                                       nullptr, D_MODEL, b2_l, D_MODEL,
                                                       offs, rowtok, rowgate, xout,
                                                       (c == 0) ? 1 : 0);
            }
        }
    }
}

// Round 5
// 922.122 us; speedup vs baseline: 2.2866x; 1.0280x over previous
//
#include <hip/hip_runtime.h>
#include <cmath>

#define D_MODEL 512
#define T_TOK   4096
#define S_SEQ   1024
#define DH_FF   2048
#define N_EXP   8
#define CAP     9216    // 8192 assignments + 8*127 pad, 128-aligned
#define QKV_LD  1536

typedef __attribute__((ext_vector_type(8))) short bf16x8_t;
typedef __attribute__((ext_vector_type(4))) float f32x4_t;
typedef _Float16 f16x8 __attribute__((ext_vector_type(8)));

__device__ __forceinline__ float gelu_exact(float x) {
    return 0.5f * x * (1.0f + erff(x * 0.70710678118654752440f));
}
__device__ __forceinline__ unsigned short f2bf(float f) {
    union { float f; unsigned int u; } v; v.f = f;
    unsigned int r = v.u + 0x7fff + ((v.u >> 16) & 1);   // RNE
    return (unsigned short)(r >> 16);
}
__device__ __forceinline__ float bf2f(unsigned short u) {
    union { unsigned int i; float f; } v; v.i = ((unsigned int)u) << 16; return v.f;
}
__device__ __forceinline__ unsigned short f2h(float f) {
    _Float16 h = (_Float16)f;
    return __builtin_bit_cast(unsigned short, h);
}
// fp32 -> fp16 hi + fp16 lo (Ootomo split): v ~= hi + lo, rel err ~2^-22
__device__ __forceinline__ void split1(float v, unsigned short& h, unsigned short& l) {
    _Float16 hf = (_Float16)v;
    _Float16 lf = (_Float16)(v - (float)hf);
    h = __builtin_bit_cast(unsigned short, hf);
    l = __builtin_bit_cast(unsigned short, lf);
}

// ---------------- LayerNorm: fp32 in -> optional {fp32, fp16 hi/lo, bf16, xcopy} ----------------
__global__ __launch_bounds__(256) void ln_kernel(
    const float* __restrict__ x, const float* __restrict__ w,
    const float* __restrict__ b, float* __restrict__ outf,
    unsigned short* __restrict__ outHi, unsigned short* __restrict__ outLo,
    unsigned short* __restrict__ outb, float* __restrict__ xcopy)
{
    const int t = blockIdx.x, tid = threadIdx.x;
    const float* xr = x + (size_t)t * D_MODEL;
    float v0 = xr[tid], v1 = xr[tid + 256];
    __shared__ float ss[256], sq[256];
    ss[tid] = v0 + v1;
    sq[tid] = v0 * v0 + v1 * v1;
    __syncthreads();
    for (int st = 128; st > 0; st >>= 1) {
        if (tid < st) { ss[tid] += ss[tid + st]; sq[tid] += sq[tid + st]; }
        __syncthreads();
    }
    float mu  = ss[0] * (1.0f / 512.0f);
    float var = sq[0] * (1.0f / 512.0f) - mu * mu;
    float rs  = rsqrtf(var + 1e-6f);
    float o0 = (v0 - mu) * rs * w[tid]       + b[tid];
    float o1 = (v1 - mu) * rs * w[tid + 256] + b[tid + 256];
    if (outf) {
        float* outr = outf + (size_t)t * D_MODEL;
        outr[tid] = o0; outr[tid + 256] = o1;
    }
    if (outHi) {
        unsigned short h0, l0, h1, l1;
        split1(o0, h0, l0); split1(o1, h1, l1);
        unsigned short* oh = outHi + (size_t)t * D_MODEL;
        unsigned short* ol = outLo + (size_t)t * D_MODEL;
        oh[tid] = h0; oh[tid + 256] = h1;
        ol[tid] = l0; ol[tid + 256] = l1;
    }
    if (outb) {
        unsigned short* ob = outb + (size_t)t * D_MODEL;
        ob[tid] = f2bf(o0); ob[tid + 256] = f2bf(o1);
    }
    if (xcopy) {
        float* xc = xcopy + (size_t)t * D_MODEL;
        xc[tid] = v0; xc[tid + 256] = v1;
    }
}

// ------- Transpose-split: fp32 [K,N] slab -> fp16 hi[N,K] + lo[N,K] (wide grid) -------
__global__ __launch_bounds__(256) void tconv_split(
    const float* __restrict__ in, int inLd, size_t eStrideIn,
    unsigned short* __restrict__ outHi, unsigned short* __restrict__ outLo,
    int outLd, size_t eStrideOut)
{
    __shared__ float Ts[32][33];
    const int tid = threadIdx.x;
    const int k0 = blockIdx.y * 32, n0 = blockIdx.x * 32;
    in    += (size_t)blockIdx.z * eStrideIn;
    outHi += (size_t)blockIdx.z * eStrideOut;
    outLo += (size_t)blockIdx.z * eStrideOut;
    int r = tid >> 3, c = (tid & 7) * 4;
    float4 v = *(const float4*)&in[(size_t)(k0 + r) * inLd + n0 + c];
    Ts[r][c] = v.x; Ts[r][c + 1] = v.y; Ts[r][c + 2] = v.z; Ts[r][c + 3] = v.w;
    __syncthreads();
    int n = tid >> 3, kk = (tid & 7) * 4;
    ushort4 h4, l4;
    split1(Ts[kk][n],     h4.x, l4.x); split1(Ts[kk + 1][n], h4.y, l4.y);
    split1(Ts[kk + 2][n], h4.z, l4.z); split1(Ts[kk + 3][n], h4.w, l4.w);
    size_t o = (size_t)(n0 + n) * outLd + k0 + kk;
    *(ushort4*)&outHi[o] = h4;
    *(ushort4*)&outLo[o] = l4;
}

// ------- Transpose-convert bf16 (L2 MoE weights, wide grid) -------
__global__ __launch_bounds__(256) void tconv(
    const float* __restrict__ in, int inLd, size_t eStrideIn,
    unsigned short* __restrict__ out, int outLd, size_t eStrideOut)
{
    __shared__ float Ts[32][33];
    const int tid = threadIdx.x;
    const int k0 = blockIdx.y * 32, n0 = blockIdx.x * 32;
    in  += (size_t)blockIdx.z * eStrideIn;
    out += (size_t)blockIdx.z * eStrideOut;
    int r = tid >> 3, c = (tid & 7) * 4;
    float4 v = *(const float4*)&in[(size_t)(k0 + r) * inLd + n0 + c];
    Ts[r][c] = v.x; Ts[r][c + 1] = v.y; Ts[r][c + 2] = v.z; Ts[r][c + 3] = v.w;
    __syncthreads();
    int n = tid >> 3, kk = (tid & 7) * 4;
    ushort4 o;
    o.x = f2bf(Ts[kk][n]);     o.y = f2bf(Ts[kk + 1][n]);
    o.z = f2bf(Ts[kk + 2][n]); o.w = f2bf(Ts[kk + 3][n]);
    *(ushort4*)&out[(size_t)(n0 + n) * outLd + k0 + kk] = o;
}

// ================= one-stage fp16x3 MFMA GEMM, 64x64 tiles, K-step 32 =================
// A pre-split hi/lo [M][K] (MODE2: gathered rows); B pre-split hi/lo [N][K] K-contig.
// MODE 0: C fp32 = acc                 (qkv, ldc=1536)
// MODE 1: C fp32 = acc + bias + resid  (o proj)
// MODE 2: Chi/Clo = split(gelu(acc+bias_e)), A gathered via rowtok (MoE up)
// MODE 5: atomicAdd(C[tok], rowgate*(acc + beta?bias_e:0)), skip pads (MoE down)
template<int MODE>
__global__ __launch_bounds__(256) void gemm_pre(
    const unsigned short* __restrict__ Ahi, const unsigned short* __restrict__ Alo,
    int lda, int KLEN,
    const unsigned short* __restrict__ Bhi, const unsigned short* __restrict__ Blo,
    size_t BeStride,
    float* __restrict__ C, int ldc,
    const float* __restrict__ bias, int biasStride,
    const float* __restrict__ resid,
    const int* __restrict__ offs, const int* __restrict__ rowtok, int beta,
    unsigned short* __restrict__ Chi, unsigned short* __restrict__ Clo)
{
    __shared__ unsigned short As_hi[64][40], As_lo[64][40];
    __shared__ unsigned short Bs_hi[64][40], Bs_lo[64][40];
    __shared__ int rt[64];
    __shared__ float rg[64];
    const int tid = threadIdx.x;
    const int row0 = blockIdx.y * 64, col0 = blockIdx.x * 64;
    int e = 0;
    if (MODE == 2 || MODE == 5) {
        #pragma unroll
        for (int i = 1; i < N_EXP; i++) if (offs[i] <= row0) e = i;
        if (tid < 64) rt[tid] = rowtok[row0 + tid];
        if (MODE == 5 && tid >= 64 && tid < 128) rg[tid - 64] = resid[row0 + tid - 64];
        __syncthreads();
    }
    const unsigned short* BeH = Bhi + (size_t)e * BeStride;
    const unsigned short* BeL = Blo + (size_t)e * BeStride;
    const int lane = tid & 63, w = tid >> 6;
    const int wrow = (w >> 1) * 32, wcol = (w & 1) * 32;
    const int m_ = lane & 15, q_ = lane >> 4;
    f32x4_t acc[2][2];
    #pragma unroll
    for (int i = 0; i < 2; i++)
        #pragma unroll
        for (int j = 0; j < 2; j++) acc[i][j] = (f32x4_t){0.f, 0.f, 0.f, 0.f};

    const int sr = tid >> 2, sc = (tid & 3) * 8;   // 64 rows x 32k: 1 uint4/thread/array
    size_t arow;
    bool azero = false;
    if (MODE == 2) {
        int t = rt[sr];
        azero = (t < 0);
        arow = (size_t)(azero ? 0 : t) * lda;
    } else {
        arow = (size_t)(row0 + sr) * lda;
    }
    const size_t brow = (size_t)(col0 + sr) * KLEN;

    for (int k0 = 0; k0 < KLEN; k0 += 32) {
        uint4 vh = azero ? make_uint4(0u, 0u, 0u, 0u) : *(const uint4*)&Ahi[arow + k0 + sc];
        uint4 vl = azero ? make_uint4(0u, 0u, 0u, 0u) : *(const uint4*)&Alo[arow + k0 + sc];
        *(uint4*)&As_hi[sr][sc] = vh;
        *(uint4*)&As_lo[sr][sc] = vl;
        *(uint4*)&Bs_hi[sr][sc] = *(const uint4*)&BeH[brow + k0 + sc];
        *(uint4*)&Bs_lo[sr][sc] = *(const uint4*)&BeL[brow + k0 + sc];
        __syncthreads();
        f16x8 ah[2], al[2], bh[2], bl[2];
        #pragma unroll
        for (int i = 0; i < 2; i++) {
            int r = wrow + 16 * i + m_;
            ah[i] = *(const f16x8*)&As_hi[r][q_ * 8];
            al[i] = *(const f16x8*)&As_lo[r][q_ * 8];
        }
        #pragma unroll
        for (int j = 0; j < 2; j++) {
            int r = wcol + 16 * j + m_;
            bh[j] = *(const f16x8*)&Bs_hi[r][q_ * 8];
            bl[j] = *(const f16x8*)&Bs_lo[r][q_ * 8];
        }
        #pragma unroll
        for (int i = 0; i < 2; i++)
            #pragma unroll
            for (int j = 0; j < 2; j++) {
                acc[i][j] = __builtin_amdgcn_mfma_f32_16x16x32_f16(ah[i], bl[j], acc[i][j], 0, 0, 0);
                acc[i][j] = __builtin_amdgcn_mfma_f32_16x16x32_f16(al[i], bh[j], acc[i][j], 0, 0, 0);
                acc[i][j] = __builtin_amdgcn_mfma_f32_16x16x32_f16(ah[i], bh[j], acc[i][j], 0, 0, 0);
            }
        __syncthreads();
    }
    // C/D layout: col = lane&15, row = (lane>>4)*4 + reg  [validated r4]
    #pragma unroll
    for (int i = 0; i < 2; i++) {
        #pragma unroll
        for (int j = 0; j < 2; j++) {
            #pragma unroll
            for (int r = 0; r < 4; r++) {
                int lr = wrow + 16 * i + q_ * 4 + r;
                int gr = row0 + lr;
                int gc = col0 + wcol + 16 * j + m_;
                float v = acc[i][j][r];
                if (MODE == 5) {
                    int t = rt[lr];
                    if (t >= 0) {
                        float add = beta ? bias[(size_t)e * biasStride + gc] : 0.0f;
                        atomicAdd(&C[(size_t)t * ldc + gc], rg[lr] * (v + add));
                    }
                } else if (MODE == 2) {
                    float g = gelu_exact(v + bias[(size_t)e * biasStride + gc]);
                    unsigned short gh, gl;
                    split1(g, gh, gl);
                    size_t idx = (size_t)gr * ldc + gc;
                    Chi[idx] = gh; Clo[idx] = gl;
                } else {
                    size_t idx = (size_t)gr * ldc + gc;
                    if (MODE == 1) C[idx] = v + bias[gc] + resid[idx];
                    else           C[idx] = v;
                }
            }
        }
    }
}

// ================= one-stage bf16 MFMA GEMM (L2 MoE), 64x64 tiles, K-step 64 =========
// MODE 2: C bf16 = gelu(acc+bias_e), A bf16 gathered via rowtok (MoE up)
// MODE 5: atomicAdd(Cout[tok], rowgate*(acc + beta?bias_e:0)), skip pads
template<int MODE>
__global__ __launch_bounds__(256) void gemm_pre_bt(
    const unsigned short* __restrict__ A, int lda, int KLEN,
    const unsigned short* __restrict__ Bt, size_t BeStride,
    unsigned short* __restrict__ C, int ldc,
    const float* __restrict__ biasBase, int biasStride,
    const int* __restrict__ offs, const int* __restrict__ rowtok,
    const float* __restrict__ rowgate, float* __restrict__ Cout, int beta)
{
    __shared__ unsigned short As[64][72];
    __shared__ unsigned short Bs[64][72];
    __shared__ int rt[64];
    __shared__ float rg[64];
    const int tid = threadIdx.x;
    const int row0 = blockIdx.y * 64, col0 = blockIdx.x * 64;
    int e = 0;
    #pragma unroll
    for (int i = 1; i < N_EXP; i++) if (offs[i] <= row0) e = i;
    if (tid < 64) rt[tid] = rowtok[row0 + tid];
    if (MODE == 5 && tid >= 64 && tid < 128) rg[tid - 64] = rowgate[row0 + tid - 64];
    __syncthreads();
    const unsigned short* Be = Bt + (size_t)e * BeStride;
    const int lane = tid & 63, w = tid >> 6;
    const int wrow = (w >> 1) * 32, wcol = (w & 1) * 32;
    const int m_ = lane & 15, q_ = lane >> 4;
    f32x4_t acc[2][2];
    #pragma unroll
    for (int i = 0; i < 2; i++)
        #pragma unroll
        for (int j = 0; j < 2; j++) acc[i][j] = (f32x4_t){0.f, 0.f, 0.f, 0.f};

    const int sr = tid >> 3, sc = (tid & 7) * 8;   // 64 rows x 64k: 2 uint4/thread/array
    size_t arow0, arow1;
    bool az0 = false, az1 = false;
    {
        int r1 = sr + 32;
        if (MODE == 2) {
            int t0 = rt[sr], t1 = rt[r1];
            az0 = (t0 < 0); az1 = (t1 < 0);
            arow0 = (size_t)(az0 ? 0 : t0) * lda;
            arow1 = (size_t)(az1 ? 0 : t1) * lda;
        } else {
            arow0 = (size_t)(row0 + sr) * lda;
            arow1 = (size_t)(row0 + r1) * lda;
        }
    }
    const size_t brow0 = (size_t)(col0 + sr) * KLEN;
    const size_t brow1 = (size_t)(col0 + sr + 32) * KLEN;

    for (int k0 = 0; k0 < KLEN; k0 += 64) {
        uint4 a0 = az0 ? make_uint4(0u, 0u, 0u, 0u) : *(const uint4*)&A[arow0 + k0 + sc];
        uint4 a1 = az1 ? make_uint4(0u, 0u, 0u, 0u) : *(const uint4*)&A[arow1 + k0 + sc];
        *(uint4*)&As[sr][sc]      = a0;
        *(uint4*)&As[sr + 32][sc] = a1;
        *(uint4*)&Bs[sr][sc]      = *(const uint4*)&Be[brow0 + k0 + sc];
        *(uint4*)&Bs[sr + 32][sc] = *(const uint4*)&Be[brow1 + k0 + sc];
        __syncthreads();
        #pragma unroll
        for (int ks = 0; ks < 2; ks++) {
            bf16x8_t af[2], bfr[2];
            #pragma unroll
            for (int i = 0; i < 2; i++)
                af[i] = *(const bf16x8_t*)&As[wrow + 16 * i + m_][ks * 32 + q_ * 8];
            #pragma unroll
            for (int j = 0; j < 2; j++)
                bfr[j] = *(const bf16x8_t*)&Bs[wcol + 16 * j + m_][ks * 32 + q_ * 8];
            #pragma unroll
            for (int i = 0; i < 2; i++)
                #pragma unroll
                for (int j = 0; j < 2; j++)
                    acc[i][j] = __builtin_amdgcn_mfma_f32_16x16x32_bf16(
                        af[i], bfr[j], acc[i][j], 0, 0, 0);
        }
        __syncthreads();
    }
    #pragma unroll
    for (int i = 0; i < 2; i++) {
        #pragma unroll
        for (int j = 0; j < 2; j++) {
            #pragma unroll
            for (int r = 0; r < 4; r++) {
                int lr = wrow + 16 * i + q_ * 4 + r;
                int gr = row0 + lr;
                int gc = col0 + wcol + 16 * j + m_;
                float v = acc[i][j][r];
                if (MODE == 5) {
                    int t = rt[lr];
                    if (t >= 0) {
                        float add = beta ? biasBase[(size_t)e * biasStride + gc] : 0.0f;
                        atomicAdd(&Cout[(size_t)t * ldc + gc], rg[lr] * (v + add));
                    }
                } else {
                    C[(size_t)gr * ldc + gc] =
                        f2bf(gelu_exact(v + biasBase[(size_t)e * biasStride + gc]));
                }
            }
        }
    }
}

// ---------------- QKV prep: fp32 qkvb slab -> fp16 head-major Q (x0.125), K, V^T ----------------
__global__ __launch_bounds__(256) void qkv_prep(
    const float* __restrict__ qkvb, unsigned short* __restrict__ Qh,
    unsigned short* __restrict__ Kh, unsigned short* __restrict__ VTh)
{
    __shared__ float Ts[64][65];
    const int tid = threadIdx.x;
    const int t0 = blockIdx.x * 64, hh = blockIdx.y, b = blockIdx.z;
    const int bh = b * 8 + hh;
    const float* src = qkvb + ((size_t)(b * S_SEQ + t0)) * QKV_LD + hh * 64;
    #pragma unroll
    for (int i = 0; i < 4; i++) {
        int flat = tid + i * 256;
        int r = flat >> 4, c4 = (flat & 15) * 4;
        float4 qv = *(const float4*)&src[(size_t)r * QKV_LD + c4];
        float4 kv = *(const float4*)&src[(size_t)r * QKV_LD + 512 + c4];
        float4 vv = *(const float4*)&src[(size_t)r * QKV_LD + 1024 + c4];
        ushort4 qo, ko;
        qo.x = f2h(qv.x * 0.125f); qo.y = f2h(qv.y * 0.125f);
        qo.z = f2h(qv.z * 0.125f); qo.w = f2h(qv.w * 0.125f);
        ko.x = f2h(kv.x); ko.y = f2h(kv.y); ko.z = f2h(kv.z); ko.w = f2h(kv.w);
        size_t o = ((size_t)bh * S_SEQ + t0 + r) * 64 + c4;
        *(ushort4*)&Qh[o] = qo;
        *(ushort4*)&Kh[o] = ko;
        Ts[r][c4] = vv.x; Ts[r][c4 + 1] = vv.y; Ts[r][c4 + 2] = vv.z; Ts[r][c4 + 3] = vv.w;
    }
    __syncthreads();
    #pragma unroll
    for (int i = 0; i < 4; i++) {
        int flat = tid + i * 256;
        int d = flat >> 4, s4 = (flat & 15) * 4;
        ushort4 vo;
        vo.x = f2h(Ts[s4][d]);     vo.y = f2h(Ts[s4 + 1][d]);
        vo.z = f2h(Ts[s4 + 2][d]); vo.w = f2h(Ts[s4 + 3][d]);
        *(ushort4*)&VTh[((size_t)bh * 64 + d) * S_SEQ + t0 + s4] = vo;
    }
}

// ---------------- Flash attention, fp16 MFMA; epilogue emits hi/lo split ----------------
__global__ __launch_bounds__(256) void flash_attn_mfma(
    const unsigned short* __restrict__ Qh, const unsigned short* __restrict__ Kh,
    const unsigned short* __restrict__ VTh,
    unsigned short* __restrict__ outHi, unsigned short* __restrict__ outLo)
{
    __shared__ unsigned short Ks[64 * 72];
    __shared__ unsigned short Vt[64 * 72];
    __shared__ unsigned short Ps[64 * 72];
    const int tid = threadIdx.x;
    const int lane = tid & 63, w = tid >> 6;
    const int m_ = lane & 15, q_ = lane >> 4;
    const int hh = blockIdx.y, b = blockIdx.z;
    const int bh = b * 8 + hh;
    const int q0 = blockIdx.x * 64;
    const size_t qbase = ((size_t)bh * S_SEQ + q0) * 64;
    const size_t kbase = (size_t)bh * S_SEQ * 64;
    const size_t vbase = (size_t)bh * 64 * S_SEQ;

    f16x8 qa[2];
    #pragma unroll
    for (int c = 0; c < 2; c++)
        qa[c] = *(const f16x8*)&Qh[qbase + (size_t)(w * 16 + m_) * 64 + c * 32 + q_ * 8];

    float m_run[4], l_run[4];
    f32x4_t acc[4];
    #pragma unroll
    for (int r = 0; r < 4; r++) { m_run[r] = -INFINITY; l_run[r] = 0.0f; }
    #pragma unroll
    for (int oj = 0; oj < 4; oj++) acc[oj] = (f32x4_t){0.f, 0.f, 0.f, 0.f};

    for (int kv0 = 0; kv0 < S_SEQ; kv0 += 64) {
        __syncthreads();
        #pragma unroll
        for (int i = 0; i < 2; i++) {
            int g = tid + i * 256;
            int r = g >> 3, c8 = (g & 7) * 8;
            *(uint4*)&Ks[r * 72 + c8] =
                *(const uint4*)&Kh[kbase + (size_t)(kv0 + r) * 64 + c8];
            *(uint4*)&Vt[r * 72 + c8] =
                *(const uint4*)&VTh[vbase + (size_t)r * S_SEQ + kv0 + c8];
        }
        __syncthreads();
        f32x4_t s[4];
        #pragma unroll
        for (int j = 0; j < 4; j++) s[j] = (f32x4_t){0.f, 0.f, 0.f, 0.f};
        #pragma unroll
        for (int c = 0; c < 2; c++)
            #pragma unroll
            for (int j = 0; j < 4; j++) {
                f16x8 kb = *(const f16x8*)&Ks[(j * 16 + m_) * 72 + c * 32 + q_ * 8];
                s[j] = __builtin_amdgcn_mfma_f32_16x16x32_f16(qa[c], kb, s[j], 0, 0, 0);
            }
        float alpha[4];
        #pragma unroll
        for (int r = 0; r < 4; r++) {
            float rm = fmaxf(fmaxf(s[0][r], s[1][r]), fmaxf(s[2][r], s[3][r]));
            #pragma unroll
            for (int mk = 1; mk < 16; mk <<= 1)
                rm = fmaxf(rm, __shfl_xor(rm, mk));
            float mn = fmaxf(m_run[r], rm);
            alpha[r] = __expf(m_run[r] - mn);
            m_run[r] = mn;
            float ps = 0.0f;
            #pragma unroll
            for (int j = 0; j < 4; j++) {
                float p = __expf(s[j][r] - mn);
                s[j][r] = p;
                ps += p;
            }
            #pragma unroll
            for (int mk = 1; mk < 16; mk <<= 1)
                ps += __shfl_xor(ps, mk);
            l_run[r] = l_run[r] * alpha[r] + ps;
        }
        #pragma unroll
        for (int oj = 0; oj < 4; oj++)
            #pragma unroll
            for (int r = 0; r < 4; r++)
                acc[oj][r] *= alpha[r];
        #pragma unroll
        for (int j = 0; j < 4; j++)
            #pragma unroll
            for (int r = 0; r < 4; r++)
                Ps[(w * 16 + q_ * 4 + r) * 72 + j * 16 + m_] = f2h(s[j][r]);
        __syncthreads();
        #pragma unroll
        for (int c = 0; c < 2; c++) {
            f16x8 pa = *(const f16x8*)&Ps[(w * 16 + m_) * 72 + c * 32 + q_ * 8];
            #pragma unroll
            for (int oj = 0; oj < 4; oj++) {
                f16x8 vb = *(const f16x8*)&Vt[(oj * 16 + m_) * 72 + c * 32 + q_ * 8];
                acc[oj] = __builtin_amdgcn_mfma_f32_16x16x32_f16(pa, vb, acc[oj], 0, 0, 0);
            }
        }
    }
    const size_t obase = ((size_t)b * S_SEQ + q0) * D_MODEL + hh * 64;
    #pragma unroll
    for (int r = 0; r < 4; r++) {
        float inv = 1.0f / l_run[r];
        #pragma unroll
        for (int oj = 0; oj < 4; oj++) {
            float v = acc[oj][r] * inv;
            unsigned short vh, vl;
            split1(v, vh, vl);
            size_t idx = obase + (size_t)(w * 16 + q_ * 4 + r) * D_MODEL + oj * 16 + m_;
            outHi[idx] = vh;
            outLo[idx] = vl;
        }
    }
}

// ---------------- Gate: 4 tokens/block, pure shuffle reduce, NO atomics ----------------
__global__ __launch_bounds__(256) void gate_kernel(
    const float* __restrict__ h, const float* __restrict__ gw,
    int* __restrict__ topi, float* __restrict__ gates)
{
    const int w = threadIdx.x >> 6, lane = threadIdx.x & 63;
    const int t = blockIdx.x * 4 + w;
    const float* hr = h + (size_t)t * D_MODEL;
    float acc[N_EXP] = {};
    for (int d = lane; d < D_MODEL; d += 64) {
        float xv = hr[d];
        const float4 g0 = *(const float4*)&gw[(size_t)d * N_EXP];
        const float4 g1 = *(const float4*)&gw[(size_t)d * N_EXP + 4];
        acc[0] += xv * g0.x; acc[1] += xv * g0.y;
        acc[2] += xv * g0.z; acc[3] += xv * g0.w;
        acc[4] += xv * g1.x; acc[5] += xv * g1.y;
        acc[6] += xv * g1.z; acc[7] += xv * g1.w;
    }
    #pragma unroll
    for (int mk = 1; mk < 64; mk <<= 1) {
        #pragma unroll
        for (int e = 0; e < N_EXP; e++) acc[e] += __shfl_xor(acc[e], mk);
    }
    if (lane == 0) {
        int e0 = 0; float v0 = acc[0];
        #pragma unroll
        for (int e = 1; e < N_EXP; e++) if (acc[e] > v0) { v0 = acc[e]; e0 = e; }
        int e1 = -1; float v1 = -INFINITY;
        #pragma unroll
        for (int e = 0; e < N_EXP; e++) if (e != e0 && acc[e] > v1) { v1 = acc[e]; e1 = e; }
        float g0 = 1.0f / (1.0f + __expf(v1 - v0));
        float g1 = 1.0f - g0;
        topi[2 * t] = e0; topi[2 * t + 1] = e1;
        gates[2 * t] = g0; gates[2 * t + 1] = g1;
    }
}

// ---------------- Route: single block, ballot-based histogram + scatter, NO atomics ----------------
__global__ __launch_bounds__(1024) void route_kernel(
    const int* __restrict__ topi, const float* __restrict__ gates,
    int* __restrict__ offs, int* __restrict__ rowtok, float* __restrict__ rowgate)
{
    __shared__ int wcnt[16][N_EXP];
    __shared__ int wbase[16][N_EXP];
    __shared__ int offs_s[N_EXP + 1];
    const int tid = threadIdx.x, w = tid >> 6, lane = tid & 63;
    const unsigned long long lt = (1ULL << lane) - 1ULL;

    int mye[8];
    int cnt[N_EXP] = {};
    #pragma unroll
    for (int r = 0; r < 8; r++) {
        int i = w * 512 + r * 64 + lane;
        int e = topi[i];
        mye[r] = e;
        #pragma unroll
        for (int e8 = 0; e8 < N_EXP; e8++) {
            unsigned long long m = __ballot(e == e8);
            cnt[e8] += (int)__popcll(m);
        }
    }
    if (lane == 0) {
        #pragma unroll
        for (int e8 = 0; e8 < N_EXP; e8++) wcnt[w][e8] = cnt[e8];
    }
    __syncthreads();
    if (tid == 0) {
        int off = 0;
        for (int e8 = 0; e8 < N_EXP; e8++) {
            offs_s[e8] = off;
            int c = 0;
            for (int ww = 0; ww < 16; ww++) c += wcnt[ww][e8];
            off += (c + 127) & ~127;
        }
        offs_s[N_EXP] = off;
        for (int e8 = 0; e8 <= N_EXP; e8++) offs[e8] = offs_s[e8];
    }
    __syncthreads();
    if (tid < 128) {
        int ww = tid >> 3, e8 = tid & 7;
        int bse = offs_s[e8];
        for (int w2 = 0; w2 < ww; w2++) bse += wcnt[w2][e8];
        wbase[ww][e8] = bse;
    }
    __syncthreads();
    int base[N_EXP];
    #pragma unroll
    for (int e8 = 0; e8 < N_EXP; e8++) base[e8] = wbase[w][e8];
    #pragma unroll
    for (int r = 0; r < 8; r++) {
        int i = w * 512 + r * 64 + lane;
        int e = mye[r];
        int pos = 0;
        #pragma unroll
        for (int e8 = 0; e8 < N_EXP; e8++) {
            unsigned long long m = __ballot(e == e8);
            if (e == e8) pos = base[e8] + (int)__popcll(m & lt);
            base[e8] += (int)__popcll(m);
        }
        rowtok[pos] = i >> 1;
        rowgate[pos] = gates[i];
    }
}

extern "C" void kernel_launch(void* const* d_in, const int* in_sizes, int n_in,
                              void* d_out, int out_size, void* d_ws, size_t ws_size,
                              hipStream_t stream)
{
    const float* x0    = (const float*)d_in[0];
    const float* ln1w  = (const float*)d_in[1];
    const float* ln1b  = (const float*)d_in[2];
    const float* wq    = (const float*)d_in[3];
    const float* wk    = (const float*)d_in[4];
    const float* wv    = (const float*)d_in[5];
    const float* wo    = (const float*)d_in[6];
    const float* bo    = (const float*)d_in[7];
    const float* ln2w  = (const float*)d_in[8];
    const float* ln2b  = (const float*)d_in[9];
    const float* gatew = (const float*)d_in[10];
    const float* w1    = (const float*)d_in[11];
    const float* b1    = (const float*)d_in[12];
    const float* w2    = (const float*)d_in[13];
    const float* b2    = (const float*)d_in[14];
    float* out = (float*)d_out;

    // ---- Time-phased workspace (peak ~46.3 MiB) ----
    // attn phase: Qh@0(4) Kh@4(4) | h_hi@8(4) h_lo@12(4) -> attn_hi@8 attn_lo@12
    //             qkvb@16(24, dead after qkv_prep) -> x1@16(8)
    //             wqkvT@40(3, dead after qkv gemm) -> VTh@40(4) | woT@44(2) | ints@46
    // MoE phase:  h2_hi@0 h2_lo@4 (L1) / h2b@0 (L2) | h2 f32@8(8, dead after gate)
    //             L1: w1T hi@8 lo@12 | w2T hi@16 lo@20 | hmid hi@24(9) lo@33(9)
    //             L2 (CHUNK=1024): w1T_bf@8(8) | w2T_bf@16(8) | hmidb@24(18)
    char* ws = (char*)d_ws;
    const size_t MiB = 1 << 20;
    unsigned short* Qh    = (unsigned short*)(ws + 0);
    unsigned short* Kh    = (unsigned short*)(ws + 4 * MiB);
    unsigned short* h_hi  = (unsigned short*)(ws + 8 * MiB);
    unsigned short* h_lo  = (unsigned short*)(ws + 12 * MiB);
    unsigned short* attn_hi = (unsigned short*)(ws + 8 * MiB);
    unsigned short* attn_lo = (unsigned short*)(ws + 12 * MiB);
    float* qkvb = (float*)(ws + 16 * MiB);
    float* x1   = (float*)(ws + 16 * MiB);
    unsigned short* wqkvT_hi = (unsigned short*)(ws + 40 * MiB);
    unsigned short* wqkvT_lo = (unsigned short*)(ws + 40 * MiB + QKV_LD * D_MODEL * 2);
    unsigned short* VTh   = (unsigned short*)(ws + 40 * MiB);
    unsigned short* woT_hi = (unsigned short*)(ws + 44 * MiB);
    unsigned short* woT_lo = (unsigned short*)(ws + 44 * MiB + D_MODEL * D_MODEL * 2);
    unsigned short* h2_hi = (unsigned short*)(ws + 0);
    unsigned short* h2_lo = (unsigned short*)(ws + 4 * MiB);
    unsigned short* h2b   = (unsigned short*)(ws + 0);
    float* h2 = (float*)(ws + 8 * MiB);
    unsigned short* w1T_hi = (unsigned short*)(ws + 8 * MiB);
    unsigned short* w1T_lo = (unsigned short*)(ws + 12 * MiB);
    unsigned short* w2T_hi = (unsigned short*)(ws + 16 * MiB);
    unsigned short* w2T_lo = (unsigned short*)(ws + 20 * MiB);
    unsigned short* hmid_hi = (unsigned short*)(ws + 24 * MiB);
    unsigned short* hmid_lo = (unsigned short*)(ws + 33 * MiB);
    unsigned short* w1T_bf  = (unsigned short*)(ws + 8 * MiB);
    unsigned short* w2T_bf  = (unsigned short*)(ws + 16 * MiB);
    unsigned short* hmidb   = (unsigned short*)(ws + 24 * MiB);
    size_t oI = 46 * MiB;
    int*   topi    = (int*)(ws + oI);
    float* gates   = (float*)(ws + oI + 2 * T_TOK * 4);
    int*   rowtok  = (int*)(ws + oI + 4 * T_TOK * 4);
    float* rowgate = (float*)(ws + oI + 4 * T_TOK * 4 + CAP * 4);
    int*   offs    = (int*)(ws + oI + 4 * T_TOK * 4 + 2 * CAP * 4);
    float* x2 = out;   // inter-layer residual lives in d_out

    const dim3 gW(16, 16, 1);          // 512x512 weight conv
    const dim3 gW8(16, 16, 8);         // per-expert chunk conv (512x512 x8)
    const dim3 gW8b(16, 32, 8);        // L2 w1 chunk conv (K=512,N=1024... N/32=32? see below)
    const dim3 gQKV(QKV_LD / 64, T_TOK / 64);    // 24 x 64
    const dim3 gO(D_MODEL / 64, T_TOK / 64);     // 8 x 64
    const dim3 gUp1(8, CAP / 64);                // L1 up: CHUNK=512
    const dim3 gDn1(D_MODEL / 64, CAP / 64);
    const dim3 gUp2(16, CAP / 64);               // L2 up: CHUNK=1024
    const dim3 gDn2(D_MODEL / 64, CAP / 64);
    const dim3 gAttn(S_SEQ / 64, 8, 4);

    for (int l = 0; l < 2; l++) {
        const float* xin = (l == 0) ? x0 : x2;
        float* xout = (l == 1) ? out : x2;
        const float* wq_l = wq + (size_t)l * D_MODEL * D_MODEL;
        const float* wk_l = wk + (size_t)l * D_MODEL * D_MODEL;
        const float* wv_l = wv + (size_t)l * D_MODEL * D_MODEL;
        const float* wo_l = wo + (size_t)l * D_MODEL * D_MODEL;
        const float* w1_l = w1 + (size_t)l * N_EXP * D_MODEL * DH_FF;
        const float* w2_l = w2 + (size_t)l * N_EXP * DH_FF * D_MODEL;
        const float* b1_l = b1 + (size_t)l * N_EXP * DH_FF;
        const float* b2_l = b2 + (size_t)l * N_EXP * D_MODEL;

        // LN1 -> h hi/lo directly
        ln_kernel<<<T_TOK, 256, 0, stream>>>(xin, ln1w + (size_t)l * D_MODEL,
                                             ln1b + (size_t)l * D_MODEL,
                                             nullptr, h_hi, h_lo, nullptr, nullptr);
        // weight convs: wqkvT [1536][512] hi/lo, woT [512][512] hi/lo
        tconv_split<<<gW, 256, 0, stream>>>(wq_l, D_MODEL, 0, wqkvT_hi, wqkvT_lo, D_MODEL, 0);
        tconv_split<<<gW, 256, 0, stream>>>(wk_l, D_MODEL, 0,
                                            wqkvT_hi + 512 * 512, wqkvT_lo + 512 * 512,
                                            D_MODEL, 0);
        tconv_split<<<gW, 256, 0, stream>>>(wv_l, D_MODEL, 0,
                                            wqkvT_hi + 1024 * 512, wqkvT_lo + 1024 * 512,
                                            D_MODEL, 0);
        tconv_split<<<gW, 256, 0, stream>>>(wo_l, D_MODEL, 0, woT_hi, woT_lo, D_MODEL, 0);
        // QKV: one GEMM, N=1536
        gemm_pre<0><<<gQKV, 256, 0, stream>>>(h_hi, h_lo, D_MODEL, D_MODEL,
                                              wqkvT_hi, wqkvT_lo, 0,
                                              qkvb, QKV_LD, nullptr, 0, nullptr,
                                              nullptr, nullptr, 0, nullptr, nullptr);
        qkv_prep<<<gAttn, 256, 0, stream>>>(qkvb, Qh, Kh, VTh);
        flash_attn_mfma<<<gAttn, 256, 0, stream>>>(Qh, Kh, VTh, attn_hi, attn_lo);
        gemm_pre<1><<<gO, 256, 0, stream>>>(attn_hi, attn_lo, D_MODEL, D_MODEL,
                                            woT_hi, woT_lo, 0,
                                            x1, D_MODEL, bo + (size_t)l * D_MODEL, 0,
                                            xin, nullptr, nullptr, 0, nullptr, nullptr);
        // LN2: h2 fp32 (gate) + split or bf16 (MoE A) + seed xout with residual
        ln_kernel<<<T_TOK, 256, 0, stream>>>(x1, ln2w + (size_t)l * D_MODEL,
                                             ln2b + (size_t)l * D_MODEL, h2,
                                             (l == 0) ? h2_hi : nullptr,
                                             (l == 0) ? h2_lo : nullptr,
                                             (l == 1) ? h2b : nullptr, xout);

        hipMemsetAsync(rowtok, 0xFF, CAP * 4, stream);
        gate_kernel<<<T_TOK / 4, 256, 0, stream>>>(h2, gatew + (size_t)l * D_MODEL * N_EXP,
                                                   topi, gates);
        route_kernel<<<1, 1024, 0, stream>>>(topi, gates, offs, rowtok, rowgate);

        if (l == 0) {
            // fp16x3 MoE, CHUNK=512: per chunk {conv w1, up, conv w2, down}
            for (int c = 0; c < 4; c++) {
                tconv_split<<<gW8, 256, 0, stream>>>(w1_l + (size_t)c * 512, DH_FF,
                                                     (size_t)D_MODEL * DH_FF,
                                                     w1T_hi, w1T_lo, D_MODEL,
                                                     (size_t)512 * D_MODEL);
                gemm_pre<2><<<gUp1, 256, 0, stream>>>(h2_hi, h2_lo, D_MODEL, D_MODEL,
                                                      w1T_hi, w1T_lo, (size_t)512 * D_MODEL,
                                                      nullptr, 512,
                                                      b1_l + (size_t)c * 512, DH_FF,
                                                      nullptr, offs, rowtok, 0,
                                                      hmid_hi, hmid_lo);
                tconv_split<<<gW8, 256, 0, stream>>>(w2_l + (size_t)c * 512 * D_MODEL,
                                                     D_MODEL, (size_t)DH_FF * D_MODEL,
                                                     w2T_hi, w2T_lo, 512,
                                                     (size_t)D_MODEL * 512);
                gemm_pre<5><<<gDn1, 256, 0, stream>>>(hmid_hi, hmid_lo, 512, 512,
                                                      w2T_hi, w2T_lo, (size_t)D_MODEL * 512,
                                                      xout, D_MODEL, b2_l, D_MODEL,
                                                      rowgate, offs, rowtok,
                                                      (c == 0) ? 1 : 0, nullptr, nullptr);
            }
        } else {
            // bf16 MoE, CHUNK=1024: per chunk {conv w1, up, conv w2, down}
            for (int c = 0; c < 2; c++) {
                tconv<<<dim3(32, 16, 8), 256, 0, stream>>>(
                    w1_l + (size_t)c * 1024, DH_FF, (size_t)D_MODEL * DH_FF,
                    w1T_bf, D_MODEL, (size_t)1024 * D_MODEL);
                gemm_pre_bt<2><<<gUp2, 256, 0, stream>>>(h2b, D_MODEL, D_MODEL,
                                                         w1T_bf, (size_t)1024 * D_MODEL,
                                                         hmidb, 1024,
                                                         b1_l + (size_t)c * 1024, DH_FF,
                                                         offs, rowtok, nullptr, nullptr, 0);
                tconv<<<dim3(16, 32, 8), 256, 0, stream>>>(
                    w2_l + (size_t)c * 1024 * D_MODEL, D_MODEL, (size_t)DH_FF * D_MODEL,
                    w2T_bf, 1024, (size_t)D_MODEL * 1024);
                gemm_pre_bt<5><<<gDn2, 256, 0, stream>>>(hmidb, 1024, 1024,
                                                         w2T_bf, (size_t)D_MODEL * 1024,
                                                         nullptr, D_MODEL, b2_l, D_MODEL,
                                                         offs, rowtok, rowgate, xout,
                                                         (c == 0) ? 1 : 0);
            }
        }
    }
}